// Round 1
// baseline (28234.412 us; speedup 1.0000x reference)
//
#include <hip/hip_runtime.h>

// ---------------------------------------------------------------------------
// Encoder: B=64, T=2048, D=256, U=256, UEP=64
//  Phase 1a: s1  = ln(x @ W + b)    -> f16   [131072][768]   (dot2 f16 GEMM)
//  Phase 1b: s1e = ln(x @ W_EP + b) -> f64   [131072][192]   (fp64 exact GEMM)
//  Phase 2 : 64 WGs (one per batch row) run the 2048-step recurrence.
//            Main GRU: Uzr f16 in registers, Uh f16 in LDS (XOR-swizzled).
//            EP GRU + is_end: full fp64 (discrete round(sigmoid) must match).
// ---------------------------------------------------------------------------

typedef _Float16 h2  __attribute__((ext_vector_type(2)));
typedef _Float16 v8h __attribute__((ext_vector_type(8)));

__device__ __forceinline__ float fdot2_(h2 a, h2 b, float c) {
#if __has_builtin(__builtin_amdgcn_fdot2)
  return __builtin_amdgcn_fdot2(a, b, c, false);
#else
  return c + (float)a[0] * (float)b[0] + (float)a[1] * (float)b[1];
#endif
}

template <int I>
__device__ __forceinline__ h2 pr(v8h v) {
  h2 r; r[0] = v[2 * I]; r[1] = v[2 * I + 1]; return r;
}

// ---------------------------------------------------------------------------
// prep: weight transposes / conversions.
// blocks: [0,768) wt | [768,1280) uzr | [1280,1536) uh(swizzled) |
//         [1536,1728) wept | [1728,1856) uepzr | [1856,1920) ueph
// ---------------------------------------------------------------------------
__global__ __launch_bounds__(256) void prep_kernel(
    const float* __restrict__ W, const float* __restrict__ U,
    const float* __restrict__ W_EP, const float* __restrict__ U_EP,
    _Float16* __restrict__ wt, _Float16* __restrict__ uzr,
    _Float16* __restrict__ uh, float* __restrict__ wept,
    float* __restrict__ uepzr, float* __restrict__ ueph)
{
  const int blk = blockIdx.x;
  const int k = threadIdx.x;
  if (blk < 768) {                       // wt[j][k] = W[k][j]  (f16)
    const int j = blk;
    wt[(size_t)j * 256 + k] = (_Float16)W[(size_t)k * 768 + j];
  } else if (blk < 1280) {               // uzr[j][k] = U[k][j], j<512 (f16)
    const int j = blk - 768;
    uzr[(size_t)j * 256 + k] = (_Float16)U[(size_t)k * 768 + j];
  } else if (blk < 1536) {               // uh swizzled: chunk c -> c ^ (j&31)
    const int j = blk - 1280;
    const int c = k >> 3, e = k & 7;
    uh[((size_t)j * 32 + (size_t)(c ^ (j & 31))) * 8 + e] =
        (_Float16)U[(size_t)k * 768 + 512 + j];
  } else if (blk < 1728) {               // wept[j][k] = W_EP[k][j] (f32)
    const int j = blk - 1536;
    wept[(size_t)j * 256 + k] = W_EP[(size_t)k * 192 + j];
  } else if (blk < 1856) {               // uepzr[c][j][e], k=4c+e, j<128
    const int j = blk - 1728;
    if (k < 64)
      uepzr[((size_t)(k >> 2) * 128 + j) * 4 + (k & 3)] = U_EP[(size_t)k * 192 + j];
  } else {                               // ueph[c][j][e], j<64
    const int j = blk - 1856;
    if (k < 64)
      ueph[((size_t)(k >> 2) * 64 + j) * 4 + (k & 3)] = U_EP[(size_t)k * 192 + 128 + j];
  }
}

// ---------------------------------------------------------------------------
// Phase 1a: main s1 = ln(x@W + b, gammas[0], betas[0]) stored f16.
// 16 rows per WG of 256 threads; dot2 f16; fused LN over 768.
// ---------------------------------------------------------------------------
__global__ __launch_bounds__(256) void ph1_main_kernel(
    const float* __restrict__ x, const _Float16* __restrict__ wt,
    const float* __restrict__ bvec, const float* __restrict__ gam,
    const float* __restrict__ bet, _Float16* __restrict__ s1out)
{
  __shared__ __align__(16) _Float16 xs[16][256];   // 8 KB
  __shared__ float sp[16][768];                    // 48 KB
  const int tid = threadIdx.x;
  const size_t row0 = (size_t)blockIdx.x * 16;

  #pragma unroll
  for (int i = 0; i < 16; ++i)
    xs[i][tid] = (_Float16)x[(row0 + i) * 256 + tid];
  __syncthreads();

  #pragma unroll 1
  for (int cc = 0; cc < 3; ++cc) {
    const int col = cc * 256 + tid;
    const v8h* wp = (const v8h*)(wt + (size_t)col * 256);
    float acc[16];
    #pragma unroll
    for (int r = 0; r < 16; ++r) acc[r] = 0.f;
    #pragma unroll 4
    for (int c = 0; c < 32; ++c) {
      const v8h w8 = wp[c];
      #pragma unroll
      for (int r = 0; r < 16; ++r) {
        const v8h x8 = *(const v8h*)(&xs[r][c * 8]);
        acc[r] = fdot2_(pr<0>(x8), pr<0>(w8), acc[r]);
        acc[r] = fdot2_(pr<1>(x8), pr<1>(w8), acc[r]);
        acc[r] = fdot2_(pr<2>(x8), pr<2>(w8), acc[r]);
        acc[r] = fdot2_(pr<3>(x8), pr<3>(w8), acc[r]);
      }
    }
    const float bb = bvec[col];
    #pragma unroll
    for (int r = 0; r < 16; ++r) sp[r][col] = acc[r] + bb;
  }
  __syncthreads();

  const int w = tid >> 6, lane = tid & 63;
  for (int rr = 0; rr < 4; ++rr) {
    const int r = (w << 2) | rr;
    float vals[12], sum = 0.f, sq = 0.f;
    #pragma unroll
    for (int j = 0; j < 12; ++j) {
      const float v = sp[r][lane + (j << 6)];
      vals[j] = v; sum += v; sq += v * v;
    }
    #pragma unroll
    for (int m = 32; m >= 1; m >>= 1) {
      sum += __shfl_xor(sum, m); sq += __shfl_xor(sq, m);
    }
    const float mean = sum * (1.f / 768.f);
    const float var = sq * (1.f / 768.f) - mean * mean;
    const float inv = 1.f / (sqrtf(var + 1e-5f) + 1e-5f);
    #pragma unroll
    for (int j = 0; j < 12; ++j) {
      const int c = lane + (j << 6);
      s1out[(row0 + r) * 768 + c] =
          (_Float16)(gam[c] * ((vals[j] - mean) * inv) + bet[c]);
    }
  }
}

// ---------------------------------------------------------------------------
// Phase 1b: EP s1e = ln(x@W_EP + b_EP) in exact fp64, stored f64 (or f32).
// ---------------------------------------------------------------------------
__global__ __launch_bounds__(192) void ph1_ep_kernel(
    const float* __restrict__ x, const float* __restrict__ wept,
    const float* __restrict__ bvec, const float* __restrict__ gam,
    const float* __restrict__ bet, void* __restrict__ s1e, const int store64)
{
  __shared__ __align__(16) float xs[16][256];   // 16 KB
  __shared__ double sp[16][192];                // 24 KB
  const int tid = threadIdx.x;
  const size_t row0 = (size_t)blockIdx.x * 16;

  for (int idx = tid; idx < 4096; idx += 192)
    xs[idx >> 8][idx & 255] = x[row0 * 256 + idx];
  __syncthreads();

  {
    const float4* wp = (const float4*)(wept + (size_t)tid * 256);
    double acc[16];
    #pragma unroll
    for (int r = 0; r < 16; ++r) acc[r] = 0.0;
    #pragma unroll 2
    for (int c = 0; c < 64; ++c) {
      const float4 w4 = wp[c];
      #pragma unroll
      for (int r = 0; r < 16; ++r) {
        const float4 x4 = *(const float4*)(&xs[r][c * 4]);
        acc[r] += (double)x4.x * (double)w4.x;
        acc[r] += (double)x4.y * (double)w4.y;
        acc[r] += (double)x4.z * (double)w4.z;
        acc[r] += (double)x4.w * (double)w4.w;
      }
    }
    const double bb = (double)bvec[tid];
    #pragma unroll
    for (int r = 0; r < 16; ++r) sp[r][tid] = acc[r] + bb;
  }
  __syncthreads();

  const int w = tid >> 6, lane = tid & 63;
  for (int r = w; r < 16; r += 3) {
    double vals[3], sum = 0.0, sq = 0.0;
    #pragma unroll
    for (int j = 0; j < 3; ++j) {
      const double v = sp[r][lane + (j << 6)];
      vals[j] = v; sum += v; sq += v * v;
    }
    #pragma unroll
    for (int m = 32; m >= 1; m >>= 1) {
      sum += __shfl_xor(sum, m); sq += __shfl_xor(sq, m);
    }
    const double mean = sum * (1.0 / 192.0);
    const double var = sq * (1.0 / 192.0) - mean * mean;
    const double den = sqrt(var + 1e-5) + 1e-5;
    #pragma unroll
    for (int j = 0; j < 3; ++j) {
      const int c = lane + (j << 6);
      const double vv = (double)gam[c] * ((vals[j] - mean) / den) + (double)bet[c];
      if (store64) ((double*)s1e)[(row0 + r) * 192 + c] = vv;
      else         ((float*)s1e)[(row0 + r) * 192 + c] = (float)vv;
    }
  }
}

// ---------------------------------------------------------------------------
// Phase 2: recurrence. 64 WGs x 512 threads. Dynamic LDS ~137 KB.
// ---------------------------------------------------------------------------
#define SCAN_LDS_BYTES 137472

__global__ __launch_bounds__(512, 2) void scan_kernel(
    const _Float16* __restrict__ uzr_g, const _Float16* __restrict__ uh_g,
    const float* __restrict__ uepzr, const float* __restrict__ ueph,
    const _Float16* __restrict__ s1, const void* __restrict__ s1e_v,
    const int s1e64, const int* __restrict__ mask,
    const float* __restrict__ gam1, const float* __restrict__ bet1,
    const float* __restrict__ gamep1, const float* __restrict__ betep1,
    const float* __restrict__ W1, const float* __restrict__ b1,
    float* __restrict__ out)
{
  extern __shared__ char smem[];
  _Float16* uh = (_Float16*)smem;                 // 131072 B (swizzled)
  double* hep  = (double*)(smem + 131072);        // 64
  double* zrE  = (double*)(smem + 131584);        // 128
  double* rhep = (double*)(smem + 132608);        // 64
  double* redd = (double*)(smem + 133120);        // 4
  float*  hf   = (float*)(smem + 133152);         // 256
  float*  zr   = (float*)(smem + 134176);         // 512
  float*  red  = (float*)(smem + 136224);         // 16
  float*  red2 = (float*)(smem + 136288);         // 8
  float*  iep  = (float*)(smem + 136320);         // 1
  h2* hh2      = (h2*)(smem + 136336);            // 128 (16B aligned)
  h2* rh       = (h2*)(smem + 136848);            // 128 (16B aligned)

  const int tid = threadIdx.x;
  const int b = blockIdx.x;
  const int lane = tid & 63;
  const int wv = tid >> 6;

  // stage Uh (pre-swizzled in global) linearly into LDS
  {
    const v8h* src = (const v8h*)uh_g;
    v8h* dst = (v8h*)smem;
    #pragma unroll
    for (int i = 0; i < 16; ++i) dst[i * 512 + tid] = src[i * 512 + tid];
  }
  // Uzr column tid -> registers (128 VGPRs as 32 x v8h)
  v8h uzrv[32];
  {
    const v8h* up = (const v8h*)(uzr_g + (size_t)tid * 256);
    #pragma unroll
    for (int c = 0; c < 32; ++c) uzrv[c] = up[c];
  }
  if (tid < 256) hf[tid] = 0.f;
  if (tid < 128) { h2 zz; zz[0] = (_Float16)0.f; zz[1] = (_Float16)0.f; hh2[tid] = zz; }
  if (tid < 64) hep[tid] = 0.0;
  if (tid == 0) iep[0] = 0.f;
  __syncthreads();

  const double b1d = (double)b1[0];

  for (int t = 0; t < 2048; ++t) {
    const size_t n = ((size_t)b << 11) | (size_t)t;
    // ---- P1: zero h if previous is_end
    float hz = 0.f;
    if (tid < 256) hz = (iep[0] > 0.5f) ? 0.f : hf[tid];
    __syncthreads();                                   // B1
    // ---- P2: commit zeroed h (f32 + f16 pairs); is_end from hep (pre-update)
    if (tid < 256) {
      hf[tid] = hz;
      const float ho = __shfl_xor(hz, 1);
      if (!(tid & 1)) { h2 p; p[0] = (_Float16)hz; p[1] = (_Float16)ho; hh2[tid >> 1] = p; }
    } else if (wv == 4) {
      double p = hep[lane] * (double)W1[lane];
      #pragma unroll
      for (int m = 32; m >= 1; m >>= 1) p += __shfl_xor(p, m);
      if (lane == 0) {
        const float e = ((p + b1d) > 0.0) ? 1.f : 0.f;
        iep[0] = e;
        out[(size_t)33554432 + n] = e;
      }
    }
    __syncthreads();                                   // B2
    // ---- P3: zr GEMV (all 512 threads, col=tid), LN over 512
    float acc;
    {
      const v8h* hv = (const v8h*)hh2;
      float a0 = 0.f, a1 = 0.f, a2 = 0.f, a3 = 0.f;
      #pragma unroll
      for (int c = 0; c < 32; ++c) {
        const v8h hc = hv[c];
        a0 = fdot2_(pr<0>(hc), pr<0>(uzrv[c]), a0);
        a1 = fdot2_(pr<1>(hc), pr<1>(uzrv[c]), a1);
        a2 = fdot2_(pr<2>(hc), pr<2>(uzrv[c]), a2);
        a3 = fdot2_(pr<3>(hc), pr<3>(uzrv[c]), a3);
      }
      acc = (a0 + a1) + (a2 + a3);
    }
    {
      float s_ = acc, q_ = acc * acc;
      #pragma unroll
      for (int m = 32; m >= 1; m >>= 1) { s_ += __shfl_xor(s_, m); q_ += __shfl_xor(q_, m); }
      if (lane == 0) { red[wv * 2] = s_; red[wv * 2 + 1] = q_; }
    }
    __syncthreads();                                   // B3
    {
      float sum = 0.f, sq = 0.f;
      #pragma unroll
      for (int i = 0; i < 8; ++i) { sum += red[i * 2]; sq += red[i * 2 + 1]; }
      const float mean = sum * (1.f / 512.f);
      const float var = sq * (1.f / 512.f) - mean * mean;
      const float inv = 1.f / (sqrtf(var + 1e-5f) + 1e-5f);
      const float s2 = gam1[tid] * ((acc - mean) * inv) + bet1[tid];
      const float s1v = (float)s1[n * 768 + tid];
      float s = 0.2f * (s1v + s2) + 0.5f;
      s = fminf(fmaxf(s, 0.f), 1.f);
      zr[tid] = s;
    }
    __syncthreads();                                   // B4
    // ---- P4: rh = r*h (f16 pairs) | EP zr GEMV fp64 (threads 256..383)
    double ve = 0.0;
    if (tid < 128) {
      const float r0 = zr[256 + 2 * tid]     * hf[2 * tid];
      const float r1 = zr[256 + 2 * tid + 1] * hf[2 * tid + 1];
      h2 p; p[0] = (_Float16)r0; p[1] = (_Float16)r1;
      rh[tid] = p;
    } else if (tid >= 256 && tid < 384) {
      const int j = tid - 256;
      const float4* wp = (const float4*)uepzr;   // [c][j][4]
      double v0 = 0.0, v1 = 0.0, v2 = 0.0, v3 = 0.0;
      #pragma unroll
      for (int c = 0; c < 16; ++c) {
        const float4 w4 = wp[c * 128 + j];
        v0 += hep[4 * c + 0] * (double)w4.x;
        v1 += hep[4 * c + 1] * (double)w4.y;
        v2 += hep[4 * c + 2] * (double)w4.z;
        v3 += hep[4 * c + 3] * (double)w4.w;
      }
      ve = (v0 + v1) + (v2 + v3);
      double es = ve, eq = ve * ve;
      #pragma unroll
      for (int m = 32; m >= 1; m >>= 1) { es += __shfl_xor(es, m); eq += __shfl_xor(eq, m); }
      if (lane == 0) { redd[(wv - 4) * 2] = es; redd[(wv - 4) * 2 + 1] = eq; }
    }
    __syncthreads();                                   // B5
    // ---- P5: hh GEMV (threads 0..255, LDS Uh swizzled) | EP LN finish
    float acch = 0.f;
    if (tid < 256) {
      const v8h* uhv = (const v8h*)smem;
      const v8h* rhv = (const v8h*)rh;
      const int base = tid * 32, sw = tid & 31;
      float a0 = 0.f, a1 = 0.f, a2 = 0.f, a3 = 0.f;
      #pragma unroll
      for (int c = 0; c < 32; ++c) {
        const v8h rc = rhv[c];
        const v8h uc = uhv[base + (c ^ sw)];
        a0 = fdot2_(pr<0>(rc), pr<0>(uc), a0);
        a1 = fdot2_(pr<1>(rc), pr<1>(uc), a1);
        a2 = fdot2_(pr<2>(rc), pr<2>(uc), a2);
        a3 = fdot2_(pr<3>(rc), pr<3>(uc), a3);
      }
      acch = (a0 + a1) + (a2 + a3);
      float s_ = acch, q_ = acch * acch;
      #pragma unroll
      for (int m = 32; m >= 1; m >>= 1) { s_ += __shfl_xor(s_, m); q_ += __shfl_xor(q_, m); }
      if (lane == 0) { red2[wv * 2] = s_; red2[wv * 2 + 1] = q_; }
    } else if (tid >= 256 && tid < 384) {
      const int j = tid - 256;
      const double sum = redd[0] + redd[2];
      const double sq  = redd[1] + redd[3];
      const double mean = sum * (1.0 / 128.0);
      const double var = sq * (1.0 / 128.0) - mean * mean;
      const double den = sqrt(var + 1e-5) + 1e-5;
      const double s2e = (double)gamep1[j] * ((ve - mean) / den) + (double)betep1[j];
      const double s1ev = s1e64 ? ((const double*)s1e_v)[n * 192 + j]
                                : (double)((const float*)s1e_v)[n * 192 + j];
      double se = 0.2 * (s1ev + s2e) + 0.5;
      se = fmin(fmax(se, 0.0), 1.0);
      zrE[j] = se;
    }
    __syncthreads();                                   // B6
    // ---- P6: main h update + store | EP rhep = r_e * hep
    if (tid < 256) {
      float sum = 0.f, sq = 0.f;
      #pragma unroll
      for (int i = 0; i < 4; ++i) { sum += red2[i * 2]; sq += red2[i * 2 + 1]; }
      const float mean = sum * (1.f / 256.f);
      const float var = sq * (1.f / 256.f) - mean * mean;
      const float inv = 1.f / (sqrtf(var + 1e-5f) + 1e-5f);
      const float hhl = gam1[512 + tid] * ((acch - mean) * inv) + bet1[512 + tid];
      const float z = zr[tid];
      const float s1h = (float)s1[n * 768 + 512 + tid];
      const float hnew = z * hz + (1.f - z) * tanhf(s1h + hhl);
      const float hout = (mask[n] > 0) ? hnew : hz;
      hf[tid] = hout;
      out[n * 256 + tid] = hout;
    } else if (wv == 4) {
      rhep[lane] = zrE[64 + lane] * hep[lane];
    }
    __syncthreads();                                   // B6b
    // ---- P7: EP hh GEMV + LN + hep update (wave 4 only)
    if (wv == 4) {
      const int j = lane;
      const float4* wp = (const float4*)ueph;    // [c][j][4]
      double v0 = 0.0, v1 = 0.0, v2 = 0.0, v3 = 0.0;
      #pragma unroll
      for (int c = 0; c < 16; ++c) {
        const float4 w4 = wp[c * 64 + j];
        v0 += rhep[4 * c + 0] * (double)w4.x;
        v1 += rhep[4 * c + 1] * (double)w4.y;
        v2 += rhep[4 * c + 2] * (double)w4.z;
        v3 += rhep[4 * c + 3] * (double)w4.w;
      }
      const double ah = (v0 + v1) + (v2 + v3);
      double es = ah, eq = ah * ah;
      #pragma unroll
      for (int m = 32; m >= 1; m >>= 1) { es += __shfl_xor(es, m); eq += __shfl_xor(eq, m); }
      const double mean = es * (1.0 / 64.0);
      const double var = eq * (1.0 / 64.0) - mean * mean;
      const double den = sqrt(var + 1e-5) + 1e-5;
      const double hhe = (double)gamep1[128 + j] * ((ah - mean) / den) + (double)betep1[128 + j];
      const double ze = zrE[j];
      const double s1eh = s1e64 ? ((const double*)s1e_v)[n * 192 + 128 + j]
                                : (double)((const float*)s1e_v)[n * 192 + 128 + j];
      const double hepn = ze * hep[j] + (1.0 - ze) * tanh(s1eh + hhe);
      if (mask[n] > 0) hep[j] = hepn;
    }
    __syncthreads();                                   // B7
  }
}

// ---------------------------------------------------------------------------
extern "C" void kernel_launch(void* const* d_in, const int* in_sizes, int n_in,
                              void* d_out, int out_size, void* d_ws, size_t ws_size,
                              hipStream_t stream)
{
  (void)in_sizes; (void)n_in; (void)out_size;
  const float* x       = (const float*)d_in[0];
  const int*   mask    = (const int*)d_in[1];
  const float* W       = (const float*)d_in[2];
  const float* U       = (const float*)d_in[3];
  const float* bvec    = (const float*)d_in[4];
  const float* gammas  = (const float*)d_in[5];
  const float* betas   = (const float*)d_in[6];
  const float* W_EP    = (const float*)d_in[7];
  const float* U_EP    = (const float*)d_in[8];
  const float* b_EP    = (const float*)d_in[9];
  const float* gammasE = (const float*)d_in[10];
  const float* betasE  = (const float*)d_in[11];
  const float* W1_EP   = (const float*)d_in[12];
  const float* b1_EP   = (const float*)d_in[13];
  float* out = (float*)d_out;

  const size_t NR = 131072;                 // B*T
  const size_t S1_SZ    = NR * 768 * 2;     // f16
  const size_t S1E64_SZ = NR * 192 * 8;     // f64
  const size_t S1E32_SZ = NR * 192 * 4;     // f32 fallback
  const size_t WSMALL = 262144 + 131072 + 393216 + 196608 + 32768 + 16384;
  const int s1e64 = (ws_size >= S1_SZ + S1E64_SZ + WSMALL) ? 1 : 0;
  const size_t S1E_SZ = s1e64 ? S1E64_SZ : S1E32_SZ;
  if (ws_size < S1_SZ + S1E32_SZ + WSMALL) return;  // cannot run

  char* ws = (char*)d_ws;
  size_t off = 0;
  void* s1e      = (void*)(ws + off);      off += S1E_SZ;
  _Float16* s1   = (_Float16*)(ws + off);  off += S1_SZ;
  _Float16* uzr  = (_Float16*)(ws + off);  off += 262144;
  _Float16* uh   = (_Float16*)(ws + off);  off += 131072;
  _Float16* wt   = (_Float16*)(ws + off);  off += 393216;
  float* wept    = (float*)(ws + off);     off += 196608;
  float* uepzr   = (float*)(ws + off);     off += 32768;
  float* ueph    = (float*)(ws + off);     off += 16384;

  prep_kernel<<<dim3(1920), dim3(256), 0, stream>>>(
      W, U, W_EP, U_EP, wt, uzr, uh, wept, uepzr, ueph);
  ph1_main_kernel<<<dim3(8192), dim3(256), 0, stream>>>(
      x, wt, bvec, gammas, betas, s1);
  ph1_ep_kernel<<<dim3(8192), dim3(192), 0, stream>>>(
      x, wept, b_EP, gammasE, betasE, s1e, s1e64);

  hipFuncSetAttribute(reinterpret_cast<const void*>(scan_kernel),
                      hipFuncAttributeMaxDynamicSharedMemorySize, SCAN_LDS_BYTES);
  scan_kernel<<<dim3(64), dim3(512), SCAN_LDS_BYTES, stream>>>(
      uzr, uh, uepzr, ueph, s1, (const void*)s1e, s1e64, mask,
      gammas + 768, betas + 768, gammasE + 192, betasE + 192,
      W1_EP, b1_EP, out);
}

// Round 2
// 27870.493 us; speedup vs baseline: 1.0131x; 1.0131x over previous
//
#include <hip/hip_runtime.h>

// ---------------------------------------------------------------------------
// Encoder: B=64, T=2048, D=256, U=256, UEP=64
//  Phase 1a: s1  = ln(x @ W + b)    -> f16   [131072][768]
//  Phase 1b: s1e = ln(x @ W_EP + b) -> f64   [131072][192]  (exact fp64)
//  Phase 2 : 64 WGs x 1024 thr run the 2048-step recurrence, 4 barriers/step.
//    Uzr: regs (64 VGPR/thr, half-cols). Uh: LDS f16 swizzled (conflict-free).
//    EP GRU + is_end: fp64 (discrete round(sigmoid) must match reference).
//    s1/s1e/mask register-prefetched 1 step ahead.
// ---------------------------------------------------------------------------

typedef _Float16 h2  __attribute__((ext_vector_type(2)));
typedef _Float16 v8h __attribute__((ext_vector_type(8)));

__device__ __forceinline__ float fdot2_(h2 a, h2 b, float c) {
#if __has_builtin(__builtin_amdgcn_fdot2)
  return __builtin_amdgcn_fdot2(a, b, c, false);
#else
  return c + (float)a[0] * (float)b[0] + (float)a[1] * (float)b[1];
#endif
}

template <int I>
__device__ __forceinline__ h2 pr(v8h v) {
  h2 r; r[0] = v[2 * I]; r[1] = v[2 * I + 1]; return r;
}

// ---------------------------------------------------------------------------
// prep: weight transposes / conversions.
// blocks: [0,768) wt | [768,1280) uzr | [1280,1536) uh(chunk-swizzled) |
//         [1536,1728) wept
// ---------------------------------------------------------------------------
__global__ __launch_bounds__(256) void prep_kernel(
    const float* __restrict__ W, const float* __restrict__ U,
    const float* __restrict__ W_EP,
    _Float16* __restrict__ wt, _Float16* __restrict__ uzr,
    _Float16* __restrict__ uh, float* __restrict__ wept)
{
  const int blk = blockIdx.x;
  const int k = threadIdx.x;
  if (blk < 768) {                       // wt[j][k] = W[k][j]  (f16)
    const int j = blk;
    wt[(size_t)j * 256 + k] = (_Float16)W[(size_t)k * 768 + j];
  } else if (blk < 1280) {               // uzr[j][k] = U[k][j], j<512 (f16)
    const int j = blk - 768;
    uzr[(size_t)j * 256 + k] = (_Float16)U[(size_t)k * 768 + j];
  } else if (blk < 1536) {               // uh chunk-swizzled for scan LDS
    const int j = blk - 1280;            // col 0..255
    const int qh = k >> 6;               // row quarter
    const int c  = (k & 63) >> 3;        // 8-elem chunk within quarter
    const int e  = k & 7;
    const int g  = (4 * j + qh) & 7;
    const size_t chunk = (size_t)j * 32 + qh * 8 + (c ^ g);
    uh[chunk * 8 + e] = (_Float16)U[(size_t)k * 768 + 512 + j];
  } else {                               // wept[j][k] = W_EP[k][j] (f32)
    const int j = blk - 1536;
    wept[(size_t)j * 256 + k] = W_EP[(size_t)k * 192 + j];
  }
}

// ---------------------------------------------------------------------------
// Phase 1a: main s1 = ln(x@W + b, gammas[0], betas[0]) stored f16.
// ---------------------------------------------------------------------------
__global__ __launch_bounds__(256) void ph1_main_kernel(
    const float* __restrict__ x, const _Float16* __restrict__ wt,
    const float* __restrict__ bvec, const float* __restrict__ gam,
    const float* __restrict__ bet, _Float16* __restrict__ s1out)
{
  __shared__ __align__(16) _Float16 xs[16][256];   // 8 KB
  __shared__ float sp[16][768];                    // 48 KB
  const int tid = threadIdx.x;
  const size_t row0 = (size_t)blockIdx.x * 16;

  #pragma unroll
  for (int i = 0; i < 16; ++i)
    xs[i][tid] = (_Float16)x[(row0 + i) * 256 + tid];
  __syncthreads();

  #pragma unroll 1
  for (int cc = 0; cc < 3; ++cc) {
    const int col = cc * 256 + tid;
    const v8h* wp = (const v8h*)(wt + (size_t)col * 256);
    float acc[16];
    #pragma unroll
    for (int r = 0; r < 16; ++r) acc[r] = 0.f;
    #pragma unroll 4
    for (int c = 0; c < 32; ++c) {
      const v8h w8 = wp[c];
      #pragma unroll
      for (int r = 0; r < 16; ++r) {
        const v8h x8 = *(const v8h*)(&xs[r][c * 8]);
        acc[r] = fdot2_(pr<0>(x8), pr<0>(w8), acc[r]);
        acc[r] = fdot2_(pr<1>(x8), pr<1>(w8), acc[r]);
        acc[r] = fdot2_(pr<2>(x8), pr<2>(w8), acc[r]);
        acc[r] = fdot2_(pr<3>(x8), pr<3>(w8), acc[r]);
      }
    }
    const float bb = bvec[col];
    #pragma unroll
    for (int r = 0; r < 16; ++r) sp[r][col] = acc[r] + bb;
  }
  __syncthreads();

  const int w = tid >> 6, lane = tid & 63;
  for (int rr = 0; rr < 4; ++rr) {
    const int r = (w << 2) | rr;
    float vals[12], sum = 0.f, sq = 0.f;
    #pragma unroll
    for (int j = 0; j < 12; ++j) {
      const float v = sp[r][lane + (j << 6)];
      vals[j] = v; sum += v; sq += v * v;
    }
    #pragma unroll
    for (int m = 32; m >= 1; m >>= 1) {
      sum += __shfl_xor(sum, m); sq += __shfl_xor(sq, m);
    }
    const float mean = sum * (1.f / 768.f);
    const float var = sq * (1.f / 768.f) - mean * mean;
    const float inv = 1.f / (sqrtf(var + 1e-5f) + 1e-5f);
    #pragma unroll
    for (int j = 0; j < 12; ++j) {
      const int c = lane + (j << 6);
      s1out[(row0 + r) * 768 + c] =
          (_Float16)(gam[c] * ((vals[j] - mean) * inv) + bet[c]);
    }
  }
}

// ---------------------------------------------------------------------------
// Phase 1b: EP s1e = ln(x@W_EP + b_EP) in exact fp64, stored f64 (or f32).
// ---------------------------------------------------------------------------
__global__ __launch_bounds__(192) void ph1_ep_kernel(
    const float* __restrict__ x, const float* __restrict__ wept,
    const float* __restrict__ bvec, const float* __restrict__ gam,
    const float* __restrict__ bet, void* __restrict__ s1e, const int store64)
{
  __shared__ __align__(16) float xs[16][256];   // 16 KB
  __shared__ double sp[16][192];                // 24 KB
  const int tid = threadIdx.x;
  const size_t row0 = (size_t)blockIdx.x * 16;

  for (int idx = tid; idx < 4096; idx += 192)
    xs[idx >> 8][idx & 255] = x[row0 * 256 + idx];
  __syncthreads();

  {
    const float4* wp = (const float4*)(wept + (size_t)tid * 256);
    double acc[16];
    #pragma unroll
    for (int r = 0; r < 16; ++r) acc[r] = 0.0;
    #pragma unroll 2
    for (int c = 0; c < 64; ++c) {
      const float4 w4 = wp[c];
      #pragma unroll
      for (int r = 0; r < 16; ++r) {
        const float4 x4 = *(const float4*)(&xs[r][c * 4]);
        acc[r] += (double)x4.x * (double)w4.x;
        acc[r] += (double)x4.y * (double)w4.y;
        acc[r] += (double)x4.z * (double)w4.z;
        acc[r] += (double)x4.w * (double)w4.w;
      }
    }
    const double bb = (double)bvec[tid];
    #pragma unroll
    for (int r = 0; r < 16; ++r) sp[r][tid] = acc[r] + bb;
  }
  __syncthreads();

  const int w = tid >> 6, lane = tid & 63;
  for (int r = w; r < 16; r += 3) {
    double vals[3], sum = 0.0, sq = 0.0;
    #pragma unroll
    for (int j = 0; j < 3; ++j) {
      const double v = sp[r][lane + (j << 6)];
      vals[j] = v; sum += v; sq += v * v;
    }
    #pragma unroll
    for (int m = 32; m >= 1; m >>= 1) {
      sum += __shfl_xor(sum, m); sq += __shfl_xor(sq, m);
    }
    const double mean = sum * (1.0 / 192.0);
    const double var = sq * (1.0 / 192.0) - mean * mean;
    const double den = sqrt(var + 1e-5) + 1e-5;
    #pragma unroll
    for (int j = 0; j < 3; ++j) {
      const int c = lane + (j << 6);
      const double vv = (double)gam[c] * ((vals[j] - mean) / den) + (double)bet[c];
      if (store64) ((double*)s1e)[(row0 + r) * 192 + c] = vv;
      else         ((float*)s1e)[(row0 + r) * 192 + c] = (float)vv;
    }
  }
}

// ---------------------------------------------------------------------------
// Phase 2: recurrence. 64 WGs x 1024 threads, 4 barriers/step.
// ---------------------------------------------------------------------------
#define OFF_UH     0        /* 131072  f16 Uh, chunk-swizzled              */
#define OFF_UEPH   131072   /* 17408   f32 ueph [64][stride 68]            */
#define OFF_HEP    148480   /* 512     f64 hep[64]                         */
#define OFF_ZEE    148992   /* 512     f64 ze[64]                          */
#define OFF_RHEP   149504   /* 512     f64 rhep[64]                        */
#define OFF_EPZRP  150016   /* 256     double2 epzrP[16]                   */
#define OFF_EPHHP  150272   /* 64      double2 ephhP[4]                    */
#define OFF_H2     150336   /* 512     f16 h (256)                         */
#define OFF_RH     150848   /* 512     f16 rh (256)                        */
#define OFF_HF     151360   /* 1024    f32 h (256)                         */
#define OFF_Z      152384   /* 1024    f32 z (256)                         */
#define OFF_ZRP    153408   /* 128     float2 zrP[16]                      */
#define OFF_HHP    153536   /* 128     float2 hhP[16]                      */
#define OFF_FLAG   153664   /* 8       f32 flag[2]                         */
#define SCAN_LDS_BYTES 153728

__global__ __launch_bounds__(1024, 4) void scan_kernel(
    const _Float16* __restrict__ uzr_g, const _Float16* __restrict__ uh_g,
    const float* __restrict__ U_EP, const _Float16* __restrict__ s1,
    const void* __restrict__ s1e_v, const int s1e64,
    const int* __restrict__ mask,
    const float* __restrict__ gam1, const float* __restrict__ bet1,
    const float* __restrict__ gamep1, const float* __restrict__ betep1,
    const float* __restrict__ W1, const float* __restrict__ b1,
    float* __restrict__ out)
{
  extern __shared__ char sm[];
  const int t  = threadIdx.x;
  const int b  = blockIdx.x;
  const int w  = t >> 6;
  const int jz = t >> 1;             // zr col (0..511), half = t&1
  const int jh = t >> 2;             // hh col (0..255), quarter = t&3
  const int qh = t & 3;
  const int je = t >> 3;             // EP-zr col (0..127), slice = t&7
  const int sl = t & 7;
  const int je2 = (t & 255) >> 2;    // EP-hh col for t<256

  float*  hf    = (float*)(sm + OFF_HF);
  float*  zArr  = (float*)(sm + OFF_Z);
  float*  flagp = (float*)(sm + OFF_FLAG);
  double* hepd  = (double*)(sm + OFF_HEP);
  double* zeE   = (double*)(sm + OFF_ZEE);
  double* rhep  = (double*)(sm + OFF_RHEP);

  // ---- stage LDS weights ----
  {
    const v8h* src = (const v8h*)uh_g;
    v8h* dst = (v8h*)(sm + OFF_UH);
    #pragma unroll
    for (int i = 0; i < 8; ++i) dst[i * 1024 + t] = src[i * 1024 + t];
  }
  {
    float* dst = (float*)(sm + OFF_UEPH);
    #pragma unroll
    for (int m = 0; m < 4; ++m) {
      const int idx = t + m * 1024;
      const int k = idx >> 6, j = idx & 63;
      dst[j * 68 + k] = U_EP[(size_t)k * 192 + 128 + j];
    }
  }
  // ---- per-thread register weights ----
  v8h uzrv[16];
  {
    const v8h* up = (const v8h*)uzr_g + (size_t)jz * 32 + (size_t)(t & 1) * 16;
    #pragma unroll
    for (int c = 0; c < 16; ++c) uzrv[c] = up[c];
  }
  float uez[8];
  #pragma unroll
  for (int i = 0; i < 8; ++i) uez[i] = U_EP[(size_t)(8 * sl + i) * 192 + je];

  // ---- constants ----
  const float gz = gam1[jz],        bz = bet1[jz];
  const float gh = gam1[512 + jh],  bh = bet1[512 + jh];
  const float gse = gamep1[je],       bse = betep1[je];
  const float ghe = gamep1[128 + je2], bhe = betep1[128 + je2];
  const float w1r = (w == 15) ? W1[t - 960] : 0.f;
  const double b1s = (double)b1[0];
  const double* dptr = (const double*)s1e_v;
  const float*  fptr = (const float*)s1e_v;

  // ---- init state ----
  if (t < 256) hf[t] = 0.f;
  if (t < 128) { h2 zz; zz[0] = (_Float16)0.f; zz[1] = (_Float16)0.f;
                 ((h2*)(sm + OFF_H2))[t] = zz; }
  if (t < 64)  hepd[t] = 0.0;
  if (t < 2)   flagp[t] = 0.f;

  // ---- prefetch step 0 ----
  const size_t n0 = (size_t)b << 11;
  float  s1zr_c = (float)s1[n0 * 768 + jz];
  float  s1h_c  = (float)s1[n0 * 768 + 512 + jh];
  double s1ezr_c = s1e64 ? dptr[n0 * 192 + je] : (double)fptr[n0 * 192 + je];
  double s1ehh_c = 0.0;
  if (t < 256)
    s1ehh_c = s1e64 ? dptr[n0 * 192 + 128 + je2] : (double)fptr[n0 * 192 + 128 + je2];
  int mask_c = mask[n0];
  __syncthreads();

  for (int tt = 0; tt < 2048; ++tt) {
    const size_t n = ((size_t)b << 11) | (size_t)tt;
    const size_t np1 = ((size_t)b << 11) | (size_t)((tt + 1 < 2048) ? tt + 1 : 2047);
    const float fz = (flagp[tt & 1] > 0.5f) ? 0.f : 1.f;

    // ---- Seg1: prefetch t+1 | zr dot | EP-zr dot | is_end ----
    const float  s1zr_n = (float)s1[np1 * 768 + jz];
    const float  s1h_n  = (float)s1[np1 * 768 + 512 + jh];
    const double s1ezr_n = s1e64 ? dptr[np1 * 192 + je] : (double)fptr[np1 * 192 + je];
    double s1ehh_n = 0.0;
    if (t < 256)
      s1ehh_n = s1e64 ? dptr[np1 * 192 + 128 + je2] : (double)fptr[np1 * 192 + 128 + je2];
    const int mask_n = mask[np1];

    float d;
    {
      float a0 = 0.f, a1 = 0.f, a2 = 0.f, a3 = 0.f;
      const v8h* hv = (const v8h*)(sm + OFF_H2) + (t & 1) * 16;
      #pragma unroll
      for (int c = 0; c < 16; ++c) {
        const v8h hc = hv[c];
        a0 = fdot2_(pr<0>(hc), pr<0>(uzrv[c]), a0);
        a1 = fdot2_(pr<1>(hc), pr<1>(uzrv[c]), a1);
        a2 = fdot2_(pr<2>(hc), pr<2>(uzrv[c]), a2);
        a3 = fdot2_(pr<3>(hc), pr<3>(uzrv[c]), a3);
      }
      d = (a0 + a1) + (a2 + a3);
      d += __shfl_xor(d, 1);
      d *= fz;
      float s_ = d, q_ = d * d;
      #pragma unroll
      for (int m = 2; m <= 32; m <<= 1) { s_ += __shfl_xor(s_, m); q_ += __shfl_xor(q_, m); }
      if ((t & 63) == 0) ((float2*)(sm + OFF_ZRP))[w] = make_float2(s_, q_);
    }
    double de;
    {
      double v0 = 0.0;
      #pragma unroll
      for (int i = 0; i < 8; ++i) v0 += hepd[8 * sl + i] * (double)uez[i];
      v0 += __shfl_xor(v0, 1); v0 += __shfl_xor(v0, 2); v0 += __shfl_xor(v0, 4);
      de = v0;
      double es = de, eq = de * de;
      #pragma unroll
      for (int m = 8; m <= 32; m <<= 1) { es += __shfl_xor(es, m); eq += __shfl_xor(eq, m); }
      if ((t & 63) == 0) ((double2*)(sm + OFF_EPZRP))[w] = make_double2(es, eq);
    }
    if (w == 15) {
      double p = hepd[t - 960] * (double)w1r;
      #pragma unroll
      for (int m = 1; m <= 32; m <<= 1) p += __shfl_xor(p, m);
      if (t == 960) {
        const float e = ((p + b1s) > 0.0) ? 1.f : 0.f;
        flagp[(tt + 1) & 1] = e;
        out[(size_t)33554432 + n] = e;
      }
    }
    __syncthreads();  // B1

    // ---- Seg2: LN512 + s,z,r,rh | EP LN128 + se,ze,rhep ----
    {
      float S = 0.f, Q = 0.f;
      const float4* zp = (const float4*)(sm + OFF_ZRP);
      #pragma unroll
      for (int i = 0; i < 8; ++i) { const float4 v = zp[i]; S += v.x + v.z; Q += v.y + v.w; }
      const float mean = S * (1.f / 512.f);
      const float var = Q * (1.f / 512.f) - mean * mean;
      const float inv = 1.f / (sqrtf(var + 1e-5f) + 1e-5f);
      if (!(t & 1)) {
        const float s2v = gz * ((d - mean) * inv) + bz;
        float sv = 0.2f * (s1zr_c + s2v) + 0.5f;
        sv = fminf(fmaxf(sv, 0.f), 1.f);
        if (jz < 256) zArr[jz] = sv;
        else {
          const float rhv = sv * (fz * hf[jz - 256]);
          ((_Float16*)(sm + OFF_RH))[jz - 256] = (_Float16)rhv;
        }
      }
    }
    if (!(t & 7)) {
      double S = 0.0, Q = 0.0;
      const double2* ep = (const double2*)(sm + OFF_EPZRP);
      #pragma unroll
      for (int i = 0; i < 16; ++i) { const double2 v = ep[i]; S += v.x; Q += v.y; }
      const double mean = S * (1.0 / 128.0);
      const double var = Q * (1.0 / 128.0) - mean * mean;
      const double den = sqrt(var + 1e-5) + 1e-5;
      const double s2e = (double)gse * ((de - mean) / den) + (double)bse;
      double se = 0.2 * (s1ezr_c + s2e) + 0.5;
      se = fmin(fmax(se, 0.0), 1.0);
      if (je < 64) zeE[je] = se;
      else         rhep[je - 64] = se * hepd[je - 64];
    }
    __syncthreads();  // B2

    // ---- Seg3: hh dot (LDS Uh swizzled) | EP-hh dot ----
    float dh;
    {
      float c0 = 0.f, c1 = 0.f, c2 = 0.f, c3 = 0.f;
      const v8h* rv = (const v8h*)(sm + OFF_RH) + qh * 8;
      const v8h* uhl = (const v8h*)(sm + OFF_UH);
      const int base = t * 8, g = t & 7;
      #pragma unroll
      for (int c = 0; c < 8; ++c) {
        const v8h rc = rv[c];
        const v8h uc = uhl[base + (c ^ g)];
        c0 = fdot2_(pr<0>(rc), pr<0>(uc), c0);
        c1 = fdot2_(pr<1>(rc), pr<1>(uc), c1);
        c2 = fdot2_(pr<2>(rc), pr<2>(uc), c2);
        c3 = fdot2_(pr<3>(rc), pr<3>(uc), c3);
      }
      dh = (c0 + c1) + (c2 + c3);
      dh += __shfl_xor(dh, 1);
      dh += __shfl_xor(dh, 2);
      float s_ = dh, q_ = dh * dh;
      #pragma unroll
      for (int m = 4; m <= 32; m <<= 1) { s_ += __shfl_xor(s_, m); q_ += __shfl_xor(q_, m); }
      if ((t & 63) == 0) ((float2*)(sm + OFF_HHP))[w] = make_float2(s_, q_);
    }
    double deh = 0.0;
    if (t < 256) {
      const float* uel = (const float*)(sm + OFF_UEPH);
      double v0 = 0.0;
      #pragma unroll
      for (int i = 0; i < 16; ++i)
        v0 += rhep[16 * qh + i] * (double)uel[je2 * 68 + 16 * qh + i];
      v0 += __shfl_xor(v0, 1); v0 += __shfl_xor(v0, 2);
      deh = v0;
      double es = deh, eq = deh * deh;
      #pragma unroll
      for (int m = 4; m <= 32; m <<= 1) { es += __shfl_xor(es, m); eq += __shfl_xor(eq, m); }
      if ((t & 63) == 0) ((double2*)(sm + OFF_EPHHP))[w] = make_double2(es, eq);
    }
    __syncthreads();  // B3

    // ---- Seg4: main h update + store | EP hep update ----
    const bool xm = mask_c > 0;
    if (!(t & 3)) {
      float S = 0.f, Q = 0.f;
      const float4* hp = (const float4*)(sm + OFF_HHP);
      #pragma unroll
      for (int i = 0; i < 8; ++i) { const float4 v = hp[i]; S += v.x + v.z; Q += v.y + v.w; }
      const float mean = S * (1.f / 256.f);
      const float var = Q * (1.f / 256.f) - mean * mean;
      const float inv = 1.f / (sqrtf(var + 1e-5f) + 1e-5f);
      const float hhv = gh * ((dh - mean) * inv) + bh;
      const float z = zArr[jh];
      const float hzf = fz * hf[jh];
      const float hn = z * hzf + (1.f - z) * tanhf(s1h_c + hhv);
      const float hc_ = xm ? hn : hzf;
      hf[jh] = hc_;
      out[n * 256 + jh] = hc_;
      const float ho = __shfl_xor(hc_, 4);
      if (!(t & 7)) {
        h2 p; p[0] = (_Float16)hc_; p[1] = (_Float16)ho;
        ((h2*)(sm + OFF_H2))[jh >> 1] = p;
      }
    } else if (t < 256 && (t & 3) == 1) {
      double S = 0.0, Q = 0.0;
      const double2* ep = (const double2*)(sm + OFF_EPHHP);
      #pragma unroll
      for (int i = 0; i < 4; ++i) { const double2 v = ep[i]; S += v.x; Q += v.y; }
      const double mean = S * (1.0 / 64.0);
      const double var = Q * (1.0 / 64.0) - mean * mean;
      const double den = sqrt(var + 1e-5) + 1e-5;
      const double hhe = (double)ghe * ((deh - mean) / den) + (double)bhe;
      const double ze = zeE[je2];
      const double hold = hepd[je2];
      const double hepn = ze * hold + (1.0 - ze) * tanh(s1ehh_c + hhe);
      hepd[je2] = xm ? hepn : hold;
    }
    __syncthreads();  // B4

    s1zr_c = s1zr_n; s1h_c = s1h_n; s1ezr_c = s1ezr_n; s1ehh_c = s1ehh_n;
    mask_c = mask_n;
  }
}

// ---------------------------------------------------------------------------
extern "C" void kernel_launch(void* const* d_in, const int* in_sizes, int n_in,
                              void* d_out, int out_size, void* d_ws, size_t ws_size,
                              hipStream_t stream)
{
  (void)in_sizes; (void)n_in; (void)out_size;
  const float* x       = (const float*)d_in[0];
  const int*   mask    = (const int*)d_in[1];
  const float* W       = (const float*)d_in[2];
  const float* U       = (const float*)d_in[3];
  const float* bvec    = (const float*)d_in[4];
  const float* gammas  = (const float*)d_in[5];
  const float* betas   = (const float*)d_in[6];
  const float* W_EP    = (const float*)d_in[7];
  const float* U_EP    = (const float*)d_in[8];
  const float* b_EP    = (const float*)d_in[9];
  const float* gammasE = (const float*)d_in[10];
  const float* betasE  = (const float*)d_in[11];
  const float* W1_EP   = (const float*)d_in[12];
  const float* b1_EP   = (const float*)d_in[13];
  float* out = (float*)d_out;

  const size_t NR = 131072;                 // B*T
  const size_t S1_SZ    = NR * 768 * 2;     // f16
  const size_t S1E64_SZ = NR * 192 * 8;     // f64
  const size_t S1E32_SZ = NR * 192 * 4;     // f32 fallback
  const size_t WSMALL = 262144 + 131072 + 393216 + 196608;
  const int s1e64 = (ws_size >= S1_SZ + S1E64_SZ + WSMALL) ? 1 : 0;
  const size_t S1E_SZ = s1e64 ? S1E64_SZ : S1E32_SZ;
  if (ws_size < S1_SZ + S1E32_SZ + WSMALL) return;  // cannot run

  char* ws = (char*)d_ws;
  size_t off = 0;
  void* s1e      = (void*)(ws + off);      off += S1E_SZ;
  _Float16* s1   = (_Float16*)(ws + off);  off += S1_SZ;
  _Float16* uzr  = (_Float16*)(ws + off);  off += 262144;
  _Float16* uh   = (_Float16*)(ws + off);  off += 131072;
  _Float16* wt   = (_Float16*)(ws + off);  off += 393216;
  float* wept    = (float*)(ws + off);     off += 196608;

  prep_kernel<<<dim3(1728), dim3(256), 0, stream>>>(
      W, U, W_EP, wt, uzr, uh, wept);
  ph1_main_kernel<<<dim3(8192), dim3(256), 0, stream>>>(
      x, wt, bvec, gammas, betas, s1);
  ph1_ep_kernel<<<dim3(8192), dim3(192), 0, stream>>>(
      x, wept, b_EP, gammasE, betasE, s1e, s1e64);

  hipFuncSetAttribute(reinterpret_cast<const void*>(scan_kernel),
                      hipFuncAttributeMaxDynamicSharedMemorySize, SCAN_LDS_BYTES);
  scan_kernel<<<dim3(64), dim3(1024), SCAN_LDS_BYTES, stream>>>(
      uzr, uh, U_EP, s1, (const void*)s1e, s1e64, mask,
      gammas + 768, betas + 768, gammasE + 192, betasE + 192,
      W1_EP, b1_EP, out);
}

// Round 3
// 20750.987 us; speedup vs baseline: 1.3606x; 1.3431x over previous
//
#include <hip/hip_runtime.h>

// ---------------------------------------------------------------------------
// Encoder: B=64, T=2048, D=256, U=256, UEP=64
//  Phase 1a: s1  = ln(x @ W + b)    -> f16   [131072][768]
//  Phase 1b: s1e = ln(x @ W_EP + b) -> f64   [131072][192]  (exact fp64)
//  Phase 2 : 64 WGs x 512 thr, 2048 steps, 4 RAW barriers/step.
//    Uzr: 128 VGPR/thread (full column). Uh: LDS chunk-major (conflict-free).
//    EP GRU + is_end: fp64 (discrete round(sigmoid) must match reference).
//    s1/s1e register-prefetched 1 step ahead; raw barriers don't drain vmcnt.
// ---------------------------------------------------------------------------

typedef _Float16 h2  __attribute__((ext_vector_type(2)));
typedef _Float16 v8h __attribute__((ext_vector_type(8)));

__device__ __forceinline__ float fdot2_(h2 a, h2 b, float c) {
#if __has_builtin(__builtin_amdgcn_fdot2)
  return __builtin_amdgcn_fdot2(a, b, c, false);
#else
  return c + (float)a[0] * (float)b[0] + (float)a[1] * (float)b[1];
#endif
}

template <int I>
__device__ __forceinline__ h2 pr(v8h v) {
  h2 r; r[0] = v[2 * I]; r[1] = v[2 * I + 1]; return r;
}

// Raw barrier: order LDS (lgkmcnt) but leave global loads/stores in flight.
__device__ __forceinline__ void wg_barrier() {
  __builtin_amdgcn_sched_barrier(0);
  asm volatile("s_waitcnt lgkmcnt(0)" ::: "memory");
  __builtin_amdgcn_sched_barrier(0);
  __builtin_amdgcn_s_barrier();
  __builtin_amdgcn_sched_barrier(0);
}

// ---------------------------------------------------------------------------
// prep: weight transposes / conversions.
// blocks: [0,768) wt | [768,1280) uzr | [1280,1536) uh chunk-major | [1536,1728) wept
// ---------------------------------------------------------------------------
__global__ __launch_bounds__(256) void prep_kernel(
    const float* __restrict__ W, const float* __restrict__ U,
    const float* __restrict__ W_EP,
    _Float16* __restrict__ wt, _Float16* __restrict__ uzr,
    _Float16* __restrict__ uh, float* __restrict__ wept)
{
  const int blk = blockIdx.x;
  const int k = threadIdx.x;
  if (blk < 768) {                       // wt[j][k] = W[k][j]  (f16)
    const int j = blk;
    wt[(size_t)j * 256 + k] = (_Float16)W[(size_t)k * 768 + j];
  } else if (blk < 1280) {               // uzr[j][k] = U[k][j], j<512 (f16)
    const int j = blk - 768;
    uzr[(size_t)j * 256 + k] = (_Float16)U[(size_t)k * 768 + j];
  } else if (blk < 1536) {               // uh chunk-major: page p=k>>3, elem k&7
    const int j = blk - 1280;            // col 0..255
    const int p = k >> 3, e = k & 7;
    uh[((size_t)p * 256 + j) * 8 + e] = (_Float16)U[(size_t)k * 768 + 512 + j];
  } else {                               // wept[j][k] = W_EP[k][j] (f32)
    const int j = blk - 1536;
    wept[(size_t)j * 256 + k] = W_EP[(size_t)k * 192 + j];
  }
}

// ---------------------------------------------------------------------------
// Phase 1a: main s1 = ln(x@W + b, gammas[0], betas[0]) stored f16.
// ---------------------------------------------------------------------------
__global__ __launch_bounds__(256) void ph1_main_kernel(
    const float* __restrict__ x, const _Float16* __restrict__ wt,
    const float* __restrict__ bvec, const float* __restrict__ gam,
    const float* __restrict__ bet, _Float16* __restrict__ s1out)
{
  __shared__ __align__(16) _Float16 xs[16][256];   // 8 KB
  __shared__ float sp[16][768];                    // 48 KB
  const int tid = threadIdx.x;
  const size_t row0 = (size_t)blockIdx.x * 16;

  #pragma unroll
  for (int i = 0; i < 16; ++i)
    xs[i][tid] = (_Float16)x[(row0 + i) * 256 + tid];
  __syncthreads();

  #pragma unroll 1
  for (int cc = 0; cc < 3; ++cc) {
    const int col = cc * 256 + tid;
    const v8h* wp = (const v8h*)(wt + (size_t)col * 256);
    float acc[16];
    #pragma unroll
    for (int r = 0; r < 16; ++r) acc[r] = 0.f;
    #pragma unroll 4
    for (int c = 0; c < 32; ++c) {
      const v8h w8 = wp[c];
      #pragma unroll
      for (int r = 0; r < 16; ++r) {
        const v8h x8 = *(const v8h*)(&xs[r][c * 8]);
        acc[r] = fdot2_(pr<0>(x8), pr<0>(w8), acc[r]);
        acc[r] = fdot2_(pr<1>(x8), pr<1>(w8), acc[r]);
        acc[r] = fdot2_(pr<2>(x8), pr<2>(w8), acc[r]);
        acc[r] = fdot2_(pr<3>(x8), pr<3>(w8), acc[r]);
      }
    }
    const float bb = bvec[col];
    #pragma unroll
    for (int r = 0; r < 16; ++r) sp[r][col] = acc[r] + bb;
  }
  __syncthreads();

  const int w = tid >> 6, lane = tid & 63;
  for (int rr = 0; rr < 4; ++rr) {
    const int r = (w << 2) | rr;
    float vals[12], sum = 0.f, sq = 0.f;
    #pragma unroll
    for (int j = 0; j < 12; ++j) {
      const float v = sp[r][lane + (j << 6)];
      vals[j] = v; sum += v; sq += v * v;
    }
    #pragma unroll
    for (int m = 32; m >= 1; m >>= 1) {
      sum += __shfl_xor(sum, m); sq += __shfl_xor(sq, m);
    }
    const float mean = sum * (1.f / 768.f);
    const float var = sq * (1.f / 768.f) - mean * mean;
    const float inv = 1.f / (sqrtf(var + 1e-5f) + 1e-5f);
    #pragma unroll
    for (int j = 0; j < 12; ++j) {
      const int c = lane + (j << 6);
      s1out[(row0 + r) * 768 + c] =
          (_Float16)(gam[c] * ((vals[j] - mean) * inv) + bet[c]);
    }
  }
}

// ---------------------------------------------------------------------------
// Phase 1b: EP s1e = ln(x@W_EP + b_EP) in exact fp64, stored f64 (or f32).
// ---------------------------------------------------------------------------
__global__ __launch_bounds__(192) void ph1_ep_kernel(
    const float* __restrict__ x, const float* __restrict__ wept,
    const float* __restrict__ bvec, const float* __restrict__ gam,
    const float* __restrict__ bet, void* __restrict__ s1e, const int store64)
{
  __shared__ __align__(16) float xs[16][256];   // 16 KB
  __shared__ double sp[16][192];                // 24 KB
  const int tid = threadIdx.x;
  const size_t row0 = (size_t)blockIdx.x * 16;

  for (int idx = tid; idx < 4096; idx += 192)
    xs[idx >> 8][idx & 255] = x[row0 * 256 + idx];
  __syncthreads();

  {
    const float4* wp = (const float4*)(wept + (size_t)tid * 256);
    double acc[16];
    #pragma unroll
    for (int r = 0; r < 16; ++r) acc[r] = 0.0;
    #pragma unroll 2
    for (int c = 0; c < 64; ++c) {
      const float4 w4 = wp[c];
      #pragma unroll
      for (int r = 0; r < 16; ++r) {
        const float4 x4 = *(const float4*)(&xs[r][c * 4]);
        acc[r] += (double)x4.x * (double)w4.x;
        acc[r] += (double)x4.y * (double)w4.y;
        acc[r] += (double)x4.z * (double)w4.z;
        acc[r] += (double)x4.w * (double)w4.w;
      }
    }
    const double bb = (double)bvec[tid];
    #pragma unroll
    for (int r = 0; r < 16; ++r) sp[r][tid] = acc[r] + bb;
  }
  __syncthreads();

  const int w = tid >> 6, lane = tid & 63;
  for (int r = w; r < 16; r += 3) {
    double vals[3], sum = 0.0, sq = 0.0;
    #pragma unroll
    for (int j = 0; j < 3; ++j) {
      const double v = sp[r][lane + (j << 6)];
      vals[j] = v; sum += v; sq += v * v;
    }
    #pragma unroll
    for (int m = 32; m >= 1; m >>= 1) {
      sum += __shfl_xor(sum, m); sq += __shfl_xor(sq, m);
    }
    const double mean = sum * (1.0 / 192.0);
    const double var = sq * (1.0 / 192.0) - mean * mean;
    const double den = sqrt(var + 1e-5) + 1e-5;
    #pragma unroll
    for (int j = 0; j < 3; ++j) {
      const int c = lane + (j << 6);
      const double vv = (double)gam[c] * ((vals[j] - mean) / den) + (double)bet[c];
      if (store64) ((double*)s1e)[(row0 + r) * 192 + c] = vv;
      else         ((float*)s1e)[(row0 + r) * 192 + c] = (float)vv;
    }
  }
}

// ---------------------------------------------------------------------------
// Phase 2 LDS map (dynamic, 144448 B)
// ---------------------------------------------------------------------------
#define OFF_UH     0        /* 131072  f16 Uh chunk-major [32 pages][256 cols][8] */
#define OFF_MASK   131072   /* 8192    int mask row                               */
#define OFF_HEP    139264   /* 512     f64 hep[64]                                */
#define OFF_ZEE    139776   /* 512     f64 ze[64]                                 */
#define OFF_RHEP   140288   /* 512     f64 rhep[64]                               */
#define OFF_EPZRP  140800   /* 128     double2 epzrP[8]                           */
#define OFF_EPHHP  140928   /* 64      double2 ephhP[4]                           */
#define OFF_H2     140992   /* 512     f16 h packed h2[128]                       */
#define OFF_RH     141504   /* 512     f16 rh packed                              */
#define OFF_HF     142016   /* 1024    f32 h[256]                                 */
#define OFF_Z      143040   /* 1024    f32 z[256]                                 */
#define OFF_ZRP    144064   /* 64      float2 zrP[8]                              */
#define OFF_HHP    144128   /* 32      float2 hhP[4]                              */
#define OFF_FLAG   144160   /* 8       f32 flag[2]                                */
#define SCAN_LDS_BYTES 144192

__global__ __launch_bounds__(512, 2) void scan_kernel(
    const _Float16* __restrict__ uzr_g, const _Float16* __restrict__ uh_g,
    const float* __restrict__ U_EP, const _Float16* __restrict__ s1,
    const void* __restrict__ s1e_v, const int s1e64,
    const int* __restrict__ mask,
    const float* __restrict__ gam1, const float* __restrict__ bet1,
    const float* __restrict__ gamep1, const float* __restrict__ betep1,
    const float* __restrict__ W1, const float* __restrict__ b1,
    float* __restrict__ out)
{
  extern __shared__ char sm[];
  const int t = threadIdx.x;
  const int b = blockIdx.x;
  const int w = t >> 6;
  const int je  = t >> 2;            // EP-zr col 0..127
  const int qe  = t & 3;             // EP K-slice
  const int jeh = (t & 255) >> 2;    // EP-hh col 0..63

  float*  hf    = (float*)(sm + OFF_HF);
  float*  flagp = (float*)(sm + OFF_FLAG);
  double* hepd  = (double*)(sm + OFF_HEP);
  int*    maskl = (int*)(sm + OFF_MASK);

  // ---- stage Uh (linear copy; layout already chunk-major) ----
  {
    const v8h* src = (const v8h*)uh_g;
    v8h* dst = (v8h*)(sm + OFF_UH);
    #pragma unroll
    for (int i = 0; i < 16; ++i) dst[i * 512 + t] = src[i * 512 + t];
  }
  // ---- stage mask row ----
  #pragma unroll
  for (int i = 0; i < 4; ++i) maskl[i * 512 + t] = mask[((size_t)b << 11) + i * 512 + t];

  // ---- Uzr full column t -> 128 VGPRs ----
  v8h uzrv[32];
  {
    const v8h* up = (const v8h*)uzr_g + (size_t)t * 32;
    #pragma unroll
    for (int c = 0; c < 32; ++c) uzrv[c] = up[c];
  }
  // ---- EP weights (f32 regs) ----
  float uez[16], ueh[16];
  #pragma unroll
  for (int i = 0; i < 16; ++i) uez[i] = U_EP[(size_t)(16 * qe + i) * 192 + je];
  #pragma unroll
  for (int i = 0; i < 16; ++i) ueh[i] = U_EP[(size_t)(16 * qe + i) * 192 + 128 + jeh];

  // ---- constants ----
  const float gz = gam1[t],                bz = bet1[t];
  const float gh = gam1[512 + (t & 255)],  bh = bet1[512 + (t & 255)];
  const float gse = gamep1[je],            bse = betep1[je];
  const float ghe = gamep1[128 + jeh],     bhe = betep1[128 + jeh];
  const double w1d = (double)W1[t & 63];
  const double b1d = (double)b1[0];
  const double* dptr = (const double*)s1e_v;
  const float*  fptr = (const float*)s1e_v;

  // ---- init state ----
  if (t < 128) { h2 z2; z2[0] = (_Float16)0.f; z2[1] = (_Float16)0.f;
                 ((h2*)(sm + OFF_H2))[t] = z2; }
  if (t < 256) hf[t] = 0.f;
  if (t < 64)  hepd[t] = 0.0;
  if (t < 2)   flagp[t] = 0.f;

  // ---- prefetch step 0 ----
  const size_t n0 = (size_t)b << 11;
  float  s1zr_c = (float)s1[n0 * 768 + t];
  float  s1h_c  = (float)s1[n0 * 768 + 512 + (t & 255)];
  double s1ezr_c = s1e64 ? dptr[n0 * 192 + je]
                         : (double)fptr[n0 * 192 + je];
  double s1ehh_c = s1e64 ? dptr[n0 * 192 + 128 + jeh]
                         : (double)fptr[n0 * 192 + 128 + jeh];
  __syncthreads();

  for (int tt = 0; tt < 2048; ++tt) {
    const size_t n = ((size_t)b << 11) | (size_t)tt;
    const float fz = (flagp[tt & 1] > 0.5f) ? 0.f : 1.f;

    // ---- Seg1: deferred h-write | prefetch t+1 | is_end | zr dot | EP-zr dot
    if (tt > 0 && t < 256) out[(n - 1) * 256 + t] = hf[t];

    const int ttn = (tt < 2047) ? tt + 1 : 2047;
    const size_t np1 = ((size_t)b << 11) | (size_t)ttn;
    const float  s1zr_n = (float)s1[np1 * 768 + t];
    const float  s1h_n  = (float)s1[np1 * 768 + 512 + (t & 255)];
    const double s1ezr_n = s1e64 ? dptr[np1 * 192 + je]
                                 : (double)fptr[np1 * 192 + je];
    const double s1ehh_n = s1e64 ? dptr[np1 * 192 + 128 + jeh]
                                 : (double)fptr[np1 * 192 + 128 + jeh];

    if (w == 7) {                       // is_end from hep (pre-update)
      double p = hepd[t & 63] * w1d;
      #pragma unroll
      for (int m = 1; m <= 32; m <<= 1) p += __shfl_xor(p, m);
      if (t == 448) {
        const float e = ((p + b1d) > 0.0) ? 1.f : 0.f;
        flagp[(tt + 1) & 1] = e;
        out[(size_t)33554432 + n] = e;
      }
    }

    float d;                            // zr dot: full-K column t
    {
      const v8h* hv = (const v8h*)(sm + OFF_H2);
      float a0 = 0.f, a1 = 0.f, a2 = 0.f, a3 = 0.f;
      #pragma unroll
      for (int c = 0; c < 32; ++c) {
        const v8h hc = hv[c];
        a0 = fdot2_(pr<0>(hc), pr<0>(uzrv[c]), a0);
        a1 = fdot2_(pr<1>(hc), pr<1>(uzrv[c]), a1);
        a2 = fdot2_(pr<2>(hc), pr<2>(uzrv[c]), a2);
        a3 = fdot2_(pr<3>(hc), pr<3>(uzrv[c]), a3);
      }
      d = ((a0 + a1) + (a2 + a3)) * fz;
      float s_ = d, q_ = d * d;
      #pragma unroll
      for (int m = 1; m <= 32; m <<= 1) { s_ += __shfl_xor(s_, m); q_ += __shfl_xor(q_, m); }
      if ((t & 63) == 0) ((float2*)(sm + OFF_ZRP))[w] = make_float2(s_, q_);
    }
    double de;                          // EP-zr dot: col je, K-slice qe
    {
      const double2* hp = (const double2*)(hepd + 16 * qe);
      double acc = 0.0;
      #pragma unroll
      for (int i = 0; i < 8; ++i) {
        const double2 hv2 = hp[i];
        acc += hv2.x * (double)uez[2 * i] + hv2.y * (double)uez[2 * i + 1];
      }
      acc += __shfl_xor(acc, 1); acc += __shfl_xor(acc, 2);
      de = acc;
      double es = de, eq = de * de;
      #pragma unroll
      for (int m = 4; m <= 32; m <<= 1) { es += __shfl_xor(es, m); eq += __shfl_xor(eq, m); }
      if ((t & 63) == 0) ((double2*)(sm + OFF_EPZRP))[w] = make_double2(es, eq);
    }
    wg_barrier();  // B1

    // ---- Seg2: LN512 -> z / rh | EP LN128 -> ze / rhep ----
    {
      float S = 0.f, Q = 0.f;
      const float4* zp = (const float4*)(sm + OFF_ZRP);
      #pragma unroll
      for (int i = 0; i < 4; ++i) { const float4 v = zp[i]; S += v.x + v.z; Q += v.y + v.w; }
      const float mean = S * (1.f / 512.f);
      const float var = Q * (1.f / 512.f) - mean * mean;
      const float inv = 1.f / (sqrtf(var + 1e-5f) + 1e-5f);
      const float s2v = gz * ((d - mean) * inv) + bz;
      float sv = 0.2f * (s1zr_c + s2v) + 0.5f;
      sv = fminf(fmaxf(sv, 0.f), 1.f);
      if (t < 256) ((float*)(sm + OFF_Z))[t] = sv;
      else {
        const float rhv = sv * (fz * hf[t - 256]);
        ((_Float16*)(sm + OFF_RH))[t - 256] = (_Float16)rhv;
      }
    }
    if ((t & 3) == 0) {                 // EP-zr finish (128 threads)
      double S = 0.0, Q = 0.0;
      const double2* ep = (const double2*)(sm + OFF_EPZRP);
      #pragma unroll
      for (int i = 0; i < 8; ++i) { S += ep[i].x; Q += ep[i].y; }
      const double mean = S * (1.0 / 128.0);
      const double var = Q * (1.0 / 128.0) - mean * mean;
      const double den = sqrt(var + 1e-5) + 1e-5;
      const double s2e = (double)gse * ((de - mean) / den) + (double)bse;
      double se = 0.2 * (s1ezr_c + s2e) + 0.5;
      se = fmin(fmax(se, 0.0), 1.0);
      if (je < 64) ((double*)(sm + OFF_ZEE))[je] = se;
      else         ((double*)(sm + OFF_RHEP))[je - 64] = se * hepd[je - 64];
    }
    wg_barrier();  // B2

    // ---- Seg3: hh dot (t<256, conflict-free pages) | EP-hh dot (t>=256) ----
    float dh = 0.f;
    double deh = 0.0;
    if (t < 256) {
      const v8h* rhv8 = (const v8h*)(sm + OFF_RH);
      const v8h* uhv  = (const v8h*)(sm + OFF_UH);
      float c0 = 0.f, c1 = 0.f, c2 = 0.f, c3 = 0.f;
      #pragma unroll
      for (int p = 0; p < 32; ++p) {
        const v8h rc = rhv8[p];
        const v8h uc = uhv[p * 256 + t];
        c0 = fdot2_(pr<0>(rc), pr<0>(uc), c0);
        c1 = fdot2_(pr<1>(rc), pr<1>(uc), c1);
        c2 = fdot2_(pr<2>(rc), pr<2>(uc), c2);
        c3 = fdot2_(pr<3>(rc), pr<3>(uc), c3);
      }
      dh = (c0 + c1) + (c2 + c3);
      float s_ = dh, q_ = dh * dh;
      #pragma unroll
      for (int m = 1; m <= 32; m <<= 1) { s_ += __shfl_xor(s_, m); q_ += __shfl_xor(q_, m); }
      if ((t & 63) == 0) ((float2*)(sm + OFF_HHP))[w] = make_float2(s_, q_);
    } else {
      const double2* rp = (const double2*)((double*)(sm + OFF_RHEP) + 16 * qe);
      double acc = 0.0;
      #pragma unroll
      for (int i = 0; i < 8; ++i) {
        const double2 rv = rp[i];
        acc += rv.x * (double)ueh[2 * i] + rv.y * (double)ueh[2 * i + 1];
      }
      acc += __shfl_xor(acc, 1); acc += __shfl_xor(acc, 2);
      deh = acc;
      double es = deh, eq = deh * deh;
      #pragma unroll
      for (int m = 4; m <= 32; m <<= 1) { es += __shfl_xor(es, m); eq += __shfl_xor(eq, m); }
      if ((t & 63) == 0) ((double2*)(sm + OFF_EPHHP))[w - 4] = make_double2(es, eq);
    }
    wg_barrier();  // B3

    // ---- Seg4: main h update | EP hep update ----
    const int xm = maskl[tt];
    if (t < 256) {
      float S = 0.f, Q = 0.f;
      const float4* hp4 = (const float4*)(sm + OFF_HHP);
      #pragma unroll
      for (int i = 0; i < 2; ++i) { const float4 v = hp4[i]; S += v.x + v.z; Q += v.y + v.w; }
      const float mean = S * (1.f / 256.f);
      const float var = Q * (1.f / 256.f) - mean * mean;
      const float inv = 1.f / (sqrtf(var + 1e-5f) + 1e-5f);
      const float hhv = gh * ((dh - mean) * inv) + bh;
      const float z = ((float*)(sm + OFF_Z))[t];
      const float hzf = fz * hf[t];
      const float hn = z * hzf + (1.f - z) * tanhf(s1h_c + hhv);
      const float hc_ = (xm > 0) ? hn : hzf;
      hf[t] = hc_;
      const float ho = __shfl_xor(hc_, 1);
      if (!(t & 1)) {
        h2 p2; p2[0] = (_Float16)hc_; p2[1] = (_Float16)ho;
        ((h2*)(sm + OFF_H2))[t >> 1] = p2;
      }
    } else if ((t & 3) == 0) {          // EP finish (64 threads, col jeh)
      double S = 0.0, Q = 0.0;
      const double2* ep = (const double2*)(sm + OFF_EPHHP);
      #pragma unroll
      for (int i = 0; i < 4; ++i) { S += ep[i].x; Q += ep[i].y; }
      const double mean = S * (1.0 / 64.0);
      const double var = Q * (1.0 / 64.0) - mean * mean;
      const double den = sqrt(var + 1e-5) + 1e-5;
      const double hhe = (double)ghe * ((deh - mean) / den) + (double)bhe;
      const double ze = ((double*)(sm + OFF_ZEE))[jeh];
      const double hold = hepd[jeh];
      const double hepn = ze * hold + (1.0 - ze) * tanh(s1ehh_c + hhe);
      hepd[jeh] = (xm > 0) ? hepn : hold;
    }
    wg_barrier();  // B4

    s1zr_c = s1zr_n; s1h_c = s1h_n; s1ezr_c = s1ezr_n; s1ehh_c = s1ehh_n;
  }
  // final h write (step 2047)
  if (t < 256) out[((((size_t)b << 11) | 2047)) * 256 + t] = hf[t];
}

// ---------------------------------------------------------------------------
extern "C" void kernel_launch(void* const* d_in, const int* in_sizes, int n_in,
                              void* d_out, int out_size, void* d_ws, size_t ws_size,
                              hipStream_t stream)
{
  (void)in_sizes; (void)n_in; (void)out_size;
  const float* x       = (const float*)d_in[0];
  const int*   mask    = (const int*)d_in[1];
  const float* W       = (const float*)d_in[2];
  const float* U       = (const float*)d_in[3];
  const float* bvec    = (const float*)d_in[4];
  const float* gammas  = (const float*)d_in[5];
  const float* betas   = (const float*)d_in[6];
  const float* W_EP    = (const float*)d_in[7];
  const float* U_EP    = (const float*)d_in[8];
  const float* b_EP    = (const float*)d_in[9];
  const float* gammasE = (const float*)d_in[10];
  const float* betasE  = (const float*)d_in[11];
  const float* W1_EP   = (const float*)d_in[12];
  const float* b1_EP   = (const float*)d_in[13];
  float* out = (float*)d_out;

  const size_t NR = 131072;                 // B*T
  const size_t S1_SZ    = NR * 768 * 2;     // f16
  const size_t S1E64_SZ = NR * 192 * 8;     // f64
  const size_t S1E32_SZ = NR * 192 * 4;     // f32 fallback
  const size_t WSMALL = 262144 + 131072 + 393216 + 196608;
  const int s1e64 = (ws_size >= S1_SZ + S1E64_SZ + WSMALL) ? 1 : 0;
  const size_t S1E_SZ = s1e64 ? S1E64_SZ : S1E32_SZ;
  if (ws_size < S1_SZ + S1E32_SZ + WSMALL) return;  // cannot run

  char* ws = (char*)d_ws;
  size_t off = 0;
  void* s1e      = (void*)(ws + off);      off += S1E_SZ;
  _Float16* s1   = (_Float16*)(ws + off);  off += S1_SZ;
  _Float16* uzr  = (_Float16*)(ws + off);  off += 262144;
  _Float16* uh   = (_Float16*)(ws + off);  off += 131072;
  _Float16* wt   = (_Float16*)(ws + off);  off += 393216;
  float* wept    = (float*)(ws + off);     off += 196608;

  prep_kernel<<<dim3(1728), dim3(256), 0, stream>>>(
      W, U, W_EP, wt, uzr, uh, wept);
  ph1_main_kernel<<<dim3(8192), dim3(256), 0, stream>>>(
      x, wt, bvec, gammas, betas, s1);
  ph1_ep_kernel<<<dim3(8192), dim3(192), 0, stream>>>(
      x, wept, b_EP, gammasE, betasE, s1e, s1e64);

  hipFuncSetAttribute(reinterpret_cast<const void*>(scan_kernel),
                      hipFuncAttributeMaxDynamicSharedMemorySize, SCAN_LDS_BYTES);
  scan_kernel<<<dim3(64), dim3(512), SCAN_LDS_BYTES, stream>>>(
      uzr, uh, U_EP, s1, (const void*)s1e, s1e64, mask,
      gammas + 768, betas + 768, gammasE + 192, betasE + 192,
      W1_EP, b1_EP, out);
}

// Round 6
// 16685.834 us; speedup vs baseline: 1.6921x; 1.2436x over previous
//
#include <hip/hip_runtime.h>

// ---------------------------------------------------------------------------
// Encoder: B=64, T=2048, D=256, U=256, UEP=64
//  Phase 1a: s1  = ln(x @ W + b)    -> f16   [131072][768]
//  Phase 1b: s1e = ln(x @ W_EP + b) -> f64   [131072][192]  (exact fp64)
//  Phase 2 : 64 WGs x 512 thr, 2048 steps, 4 RAW barriers/step.
//    Uzr: 128 VGPR/thread as float[128], each component pinned with a SCALAR
//         asm volatile("" : "+v") so loads can't be sunk/rematerialized.
//    Uh: LDS chunk-major pages (conflict-free).
//    EP GRU + is_end: fp64 (discrete round(sigmoid) must match reference).
//    s1/s1e register-prefetched 1 step ahead; raw barriers don't drain vmcnt.
// ---------------------------------------------------------------------------

typedef _Float16 h2  __attribute__((ext_vector_type(2)));
typedef _Float16 v8h __attribute__((ext_vector_type(8)));

__device__ __forceinline__ float fdot2_(h2 a, h2 b, float c) {
#if __has_builtin(__builtin_amdgcn_fdot2)
  return __builtin_amdgcn_fdot2(a, b, c, false);
#else
  return c + (float)a[0] * (float)b[0] + (float)a[1] * (float)b[1];
#endif
}

template <int I>
__device__ __forceinline__ h2 pr(v8h v) {
  h2 r; r[0] = v[2 * I]; r[1] = v[2 * I + 1]; return r;
}

// Raw barrier: order LDS (lgkmcnt) but leave global loads/stores in flight.
__device__ __forceinline__ void wg_barrier() {
  __builtin_amdgcn_sched_barrier(0);
  asm volatile("s_waitcnt lgkmcnt(0)" ::: "memory");
  __builtin_amdgcn_sched_barrier(0);
  __builtin_amdgcn_s_barrier();
  __builtin_amdgcn_sched_barrier(0);
}

// ---------------------------------------------------------------------------
// prep: weight transposes / conversions.
// blocks: [0,768) wt | [768,1280) uzr | [1280,1536) uh chunk-major | [1536,1728) wept
// ---------------------------------------------------------------------------
__global__ __launch_bounds__(256) void prep_kernel(
    const float* __restrict__ W, const float* __restrict__ U,
    const float* __restrict__ W_EP,
    _Float16* __restrict__ wt, _Float16* __restrict__ uzr,
    _Float16* __restrict__ uh, float* __restrict__ wept)
{
  const int blk = blockIdx.x;
  const int k = threadIdx.x;
  if (blk < 768) {                       // wt[j][k] = W[k][j]  (f16)
    const int j = blk;
    wt[(size_t)j * 256 + k] = (_Float16)W[(size_t)k * 768 + j];
  } else if (blk < 1280) {               // uzr[j][k] = U[k][j], j<512 (f16)
    const int j = blk - 768;
    uzr[(size_t)j * 256 + k] = (_Float16)U[(size_t)k * 768 + j];
  } else if (blk < 1536) {               // uh chunk-major: page p=k>>3, elem k&7
    const int j = blk - 1280;            // col 0..255
    const int p = k >> 3, e = k & 7;
    uh[((size_t)p * 256 + j) * 8 + e] = (_Float16)U[(size_t)k * 768 + 512 + j];
  } else {                               // wept[j][k] = W_EP[k][j] (f32)
    const int j = blk - 1536;
    wept[(size_t)j * 256 + k] = W_EP[(size_t)k * 192 + j];
  }
}

// ---------------------------------------------------------------------------
// Phase 1a: main s1 = ln(x@W + b, gammas[0], betas[0]) stored f16.
// ---------------------------------------------------------------------------
__global__ __launch_bounds__(256) void ph1_main_kernel(
    const float* __restrict__ x, const _Float16* __restrict__ wt,
    const float* __restrict__ bvec, const float* __restrict__ gam,
    const float* __restrict__ bet, _Float16* __restrict__ s1out)
{
  __shared__ __align__(16) _Float16 xs[16][256];   // 8 KB
  __shared__ float sp[16][768];                    // 48 KB
  const int tid = threadIdx.x;
  const size_t row0 = (size_t)blockIdx.x * 16;

  #pragma unroll
  for (int i = 0; i < 16; ++i)
    xs[i][tid] = (_Float16)x[(row0 + i) * 256 + tid];
  __syncthreads();

  #pragma unroll 1
  for (int cc = 0; cc < 3; ++cc) {
    const int col = cc * 256 + tid;
    const v8h* wp = (const v8h*)(wt + (size_t)col * 256);
    float acc[16];
    #pragma unroll
    for (int r = 0; r < 16; ++r) acc[r] = 0.f;
    #pragma unroll 4
    for (int c = 0; c < 32; ++c) {
      const v8h w8 = wp[c];
      #pragma unroll
      for (int r = 0; r < 16; ++r) {
        const v8h x8 = *(const v8h*)(&xs[r][c * 8]);
        acc[r] = fdot2_(pr<0>(x8), pr<0>(w8), acc[r]);
        acc[r] = fdot2_(pr<1>(x8), pr<1>(w8), acc[r]);
        acc[r] = fdot2_(pr<2>(x8), pr<2>(w8), acc[r]);
        acc[r] = fdot2_(pr<3>(x8), pr<3>(w8), acc[r]);
      }
    }
    const float bb = bvec[col];
    #pragma unroll
    for (int r = 0; r < 16; ++r) sp[r][col] = acc[r] + bb;
  }
  __syncthreads();

  const int w = tid >> 6, lane = tid & 63;
  for (int rr = 0; rr < 4; ++rr) {
    const int r = (w << 2) | rr;
    float vals[12], sum = 0.f, sq = 0.f;
    #pragma unroll
    for (int j = 0; j < 12; ++j) {
      const float v = sp[r][lane + (j << 6)];
      vals[j] = v; sum += v; sq += v * v;
    }
    #pragma unroll
    for (int m = 32; m >= 1; m >>= 1) {
      sum += __shfl_xor(sum, m); sq += __shfl_xor(sq, m);
    }
    const float mean = sum * (1.f / 768.f);
    const float var = sq * (1.f / 768.f) - mean * mean;
    const float inv = 1.f / (sqrtf(var + 1e-5f) + 1e-5f);
    #pragma unroll
    for (int j = 0; j < 12; ++j) {
      const int c = lane + (j << 6);
      s1out[(row0 + r) * 768 + c] =
          (_Float16)(gam[c] * ((vals[j] - mean) * inv) + bet[c]);
    }
  }
}

// ---------------------------------------------------------------------------
// Phase 1b: EP s1e = ln(x@W_EP + b_EP) in exact fp64, stored f64 (or f32).
// ---------------------------------------------------------------------------
__global__ __launch_bounds__(192) void ph1_ep_kernel(
    const float* __restrict__ x, const float* __restrict__ wept,
    const float* __restrict__ bvec, const float* __restrict__ gam,
    const float* __restrict__ bet, void* __restrict__ s1e, const int store64)
{
  __shared__ __align__(16) float xs[16][256];   // 16 KB
  __shared__ double sp[16][192];                // 24 KB
  const int tid = threadIdx.x;
  const size_t row0 = (size_t)blockIdx.x * 16;

  for (int idx = tid; idx < 4096; idx += 192)
    xs[idx >> 8][idx & 255] = x[row0 * 256 + idx];
  __syncthreads();

  {
    const float4* wp = (const float4*)(wept + (size_t)tid * 256);
    double acc[16];
    #pragma unroll
    for (int r = 0; r < 16; ++r) acc[r] = 0.0;
    #pragma unroll 2
    for (int c = 0; c < 64; ++c) {
      const float4 w4 = wp[c];
      #pragma unroll
      for (int r = 0; r < 16; ++r) {
        const float4 x4 = *(const float4*)(&xs[r][c * 4]);
        acc[r] += (double)x4.x * (double)w4.x;
        acc[r] += (double)x4.y * (double)w4.y;
        acc[r] += (double)x4.z * (double)w4.z;
        acc[r] += (double)x4.w * (double)w4.w;
      }
    }
    const double bb = (double)bvec[tid];
    #pragma unroll
    for (int r = 0; r < 16; ++r) sp[r][tid] = acc[r] + bb;
  }
  __syncthreads();

  const int w = tid >> 6, lane = tid & 63;
  for (int r = w; r < 16; r += 3) {
    double vals[3], sum = 0.0, sq = 0.0;
    #pragma unroll
    for (int j = 0; j < 3; ++j) {
      const double v = sp[r][lane + (j << 6)];
      vals[j] = v; sum += v; sq += v * v;
    }
    #pragma unroll
    for (int m = 32; m >= 1; m >>= 1) {
      sum += __shfl_xor(sum, m); sq += __shfl_xor(sq, m);
    }
    const double mean = sum * (1.0 / 192.0);
    const double var = sq * (1.0 / 192.0) - mean * mean;
    const double den = sqrt(var + 1e-5) + 1e-5;
    #pragma unroll
    for (int j = 0; j < 3; ++j) {
      const int c = lane + (j << 6);
      const double vv = (double)gam[c] * ((vals[j] - mean) / den) + (double)bet[c];
      if (store64) ((double*)s1e)[(row0 + r) * 192 + c] = vv;
      else         ((float*)s1e)[(row0 + r) * 192 + c] = (float)vv;
    }
  }
}

// ---------------------------------------------------------------------------
// Phase 2 LDS map (dynamic, 144192 B)
// ---------------------------------------------------------------------------
#define OFF_UH     0        /* 131072  f16 Uh chunk-major [32 pages][256 cols][8] */
#define OFF_MASK   131072   /* 8192    int mask row                               */
#define OFF_HEP    139264   /* 512     f64 hep[64]                                */
#define OFF_ZEE    139776   /* 512     f64 ze[64]                                 */
#define OFF_RHEP   140288   /* 512     f64 rhep[64]                               */
#define OFF_EPZRP  140800   /* 128     double2 epzrP[8]                           */
#define OFF_EPHHP  140928   /* 64      double2 ephhP[4]                           */
#define OFF_H2     140992   /* 512     f16 h packed h2[128]                       */
#define OFF_RH     141504   /* 512     f16 rh packed                              */
#define OFF_HF     142016   /* 1024    f32 h[256]                                 */
#define OFF_Z      143040   /* 1024    f32 z[256]                                 */
#define OFF_ZRP    144064   /* 64      float2 zrP[8]                              */
#define OFF_HHP    144128   /* 32      float2 hhP[4]                              */
#define OFF_FLAG   144160   /* 8       f32 flag[2]                                */
#define SCAN_LDS_BYTES 144192

__global__ __launch_bounds__(512, 2) void scan_kernel(
    const _Float16* __restrict__ uzr_g, const _Float16* __restrict__ uh_g,
    const float* __restrict__ U_EP, const _Float16* __restrict__ s1,
    const void* __restrict__ s1e_v, const int s1e64,
    const int* __restrict__ mask,
    const float* __restrict__ gam1, const float* __restrict__ bet1,
    const float* __restrict__ gamep1, const float* __restrict__ betep1,
    const float* __restrict__ W1, const float* __restrict__ b1,
    float* __restrict__ out)
{
  extern __shared__ char sm[];
  const int t = threadIdx.x;
  const int b = blockIdx.x;
  const int w = t >> 6;
  const int je  = t >> 2;            // EP-zr col 0..127
  const int qe  = t & 3;             // EP K-slice
  const int jeh = (t & 255) >> 2;    // EP-hh col 0..63

  float*  hf    = (float*)(sm + OFF_HF);
  float*  flagp = (float*)(sm + OFF_FLAG);
  double* hepd  = (double*)(sm + OFF_HEP);
  int*    maskl = (int*)(sm + OFF_MASK);

  // ---- stage Uh (linear copy; layout already chunk-major) ----
  {
    const v8h* src = (const v8h*)uh_g;
    v8h* dst = (v8h*)(sm + OFF_UH);
    #pragma unroll
    for (int i = 0; i < 16; ++i) dst[i * 512 + t] = src[i * 512 + t];
  }
  // ---- stage mask row ----
  #pragma unroll
  for (int i = 0; i < 4; ++i) maskl[i * 512 + t] = mask[((size_t)b << 11) + i * 512 + t];

  // ---- Uzr full column t -> float[128], scalar-pinned (no remat/sink) ----
  float uz[128];
  {
    const float4* up = (const float4*)uzr_g + (size_t)t * 32;
    #pragma unroll
    for (int c = 0; c < 32; ++c) {
      const float4 v = up[c];
      uz[4 * c + 0] = v.x; uz[4 * c + 1] = v.y;
      uz[4 * c + 2] = v.z; uz[4 * c + 3] = v.w;
    }
  }
  #pragma unroll
  for (int i = 0; i < 128; ++i) asm volatile("" : "+v"(uz[i]));

  // ---- EP weights (f32 regs) ----
  float uez[16], ueh[16];
  #pragma unroll
  for (int i = 0; i < 16; ++i) uez[i] = U_EP[(size_t)(16 * qe + i) * 192 + je];
  #pragma unroll
  for (int i = 0; i < 16; ++i) ueh[i] = U_EP[(size_t)(16 * qe + i) * 192 + 128 + jeh];

  // ---- constants ----
  const float gz = gam1[t],                bz = bet1[t];
  const float gh = gam1[512 + (t & 255)],  bh = bet1[512 + (t & 255)];
  const float gse = gamep1[je],            bse = betep1[je];
  const float ghe = gamep1[128 + jeh],     bhe = betep1[128 + jeh];
  const double w1d = (double)W1[t & 63];
  const double b1d = (double)b1[0];
  const double* dptr = (const double*)s1e_v;
  const float*  fptr = (const float*)s1e_v;

  // ---- init state ----
  if (t < 128) { h2 z2; z2[0] = (_Float16)0.f; z2[1] = (_Float16)0.f;
                 ((h2*)(sm + OFF_H2))[t] = z2; }
  if (t < 256) hf[t] = 0.f;
  if (t < 64)  hepd[t] = 0.0;
  if (t < 2)   flagp[t] = 0.f;

  // ---- prefetch step 0 ----
  const size_t n0 = (size_t)b << 11;
  float  s1zr_c = (float)s1[n0 * 768 + t];
  float  s1h_c  = (float)s1[n0 * 768 + 512 + (t & 255)];
  double s1ezr_c = s1e64 ? dptr[n0 * 192 + je]
                         : (double)fptr[n0 * 192 + je];
  double s1ehh_c = s1e64 ? dptr[n0 * 192 + 128 + jeh]
                         : (double)fptr[n0 * 192 + 128 + jeh];
  __syncthreads();

  for (int tt = 0; tt < 2048; ++tt) {
    const size_t n = ((size_t)b << 11) | (size_t)tt;
    const float fz = (flagp[tt & 1] > 0.5f) ? 0.f : 1.f;

    // ---- Seg1: deferred h-write | prefetch t+1 | is_end | zr dot | EP-zr dot
    if (tt > 0 && t < 256) out[(n - 1) * 256 + t] = hf[t];

    const int ttn = (tt < 2047) ? tt + 1 : 2047;
    const size_t np1 = ((size_t)b << 11) | (size_t)ttn;
    const float  s1zr_n = (float)s1[np1 * 768 + t];
    const float  s1h_n  = (float)s1[np1 * 768 + 512 + (t & 255)];
    const double s1ezr_n = s1e64 ? dptr[np1 * 192 + je]
                                 : (double)fptr[np1 * 192 + je];
    const double s1ehh_n = s1e64 ? dptr[np1 * 192 + 128 + jeh]
                                 : (double)fptr[np1 * 192 + 128 + jeh];

    if (w == 7) {                       // is_end from hep (pre-update)
      double p = hepd[t & 63] * w1d;
      #pragma unroll
      for (int m = 1; m <= 32; m <<= 1) p += __shfl_xor(p, m);
      if (t == 448) {
        const float e = ((p + b1d) > 0.0) ? 1.f : 0.f;
        flagp[(tt + 1) & 1] = e;
        out[(size_t)33554432 + n] = e;
      }
    }

    float d;                            // zr dot: full-K column t
    {
      const v8h* hv = (const v8h*)(sm + OFF_H2);
      float a0 = 0.f, a1 = 0.f, a2 = 0.f, a3 = 0.f;
      #pragma unroll
      for (int c = 0; c < 32; ++c) {
        const v8h hc = hv[c];
        a0 = fdot2_(pr<0>(hc), __builtin_bit_cast(h2, uz[4 * c + 0]), a0);
        a1 = fdot2_(pr<1>(hc), __builtin_bit_cast(h2, uz[4 * c + 1]), a1);
        a2 = fdot2_(pr<2>(hc), __builtin_bit_cast(h2, uz[4 * c + 2]), a2);
        a3 = fdot2_(pr<3>(hc), __builtin_bit_cast(h2, uz[4 * c + 3]), a3);
      }
      d = ((a0 + a1) + (a2 + a3)) * fz;
      float s_ = d, q_ = d * d;
      #pragma unroll
      for (int m = 1; m <= 32; m <<= 1) { s_ += __shfl_xor(s_, m); q_ += __shfl_xor(q_, m); }
      if ((t & 63) == 0) ((float2*)(sm + OFF_ZRP))[w] = make_float2(s_, q_);
    }
    double de;                          // EP-zr dot: col je, K-slice qe
    {
      const double2* hp = (const double2*)(hepd + 16 * qe);
      double acc = 0.0;
      #pragma unroll
      for (int i = 0; i < 8; ++i) {
        const double2 hv2 = hp[i];
        acc += hv2.x * (double)uez[2 * i] + hv2.y * (double)uez[2 * i + 1];
      }
      acc += __shfl_xor(acc, 1); acc += __shfl_xor(acc, 2);
      de = acc;
      double es = de, eq = de * de;
      #pragma unroll
      for (int m = 4; m <= 32; m <<= 1) { es += __shfl_xor(es, m); eq += __shfl_xor(eq, m); }
      if ((t & 63) == 0) ((double2*)(sm + OFF_EPZRP))[w] = make_double2(es, eq);
    }
    wg_barrier();  // B1

    // ---- Seg2: LN512 -> z / rh | EP LN128 -> ze / rhep ----
    {
      float S = 0.f, Q = 0.f;
      const float4* zp = (const float4*)(sm + OFF_ZRP);
      #pragma unroll
      for (int i = 0; i < 4; ++i) { const float4 v = zp[i]; S += v.x + v.z; Q += v.y + v.w; }
      const float mean = S * (1.f / 512.f);
      const float var = Q * (1.f / 512.f) - mean * mean;
      const float inv = 1.f / (sqrtf(var + 1e-5f) + 1e-5f);
      const float s2v = gz * ((d - mean) * inv) + bz;
      float sv = 0.2f * (s1zr_c + s2v) + 0.5f;
      sv = fminf(fmaxf(sv, 0.f), 1.f);
      if (t < 256) ((float*)(sm + OFF_Z))[t] = sv;
      else {
        const float rhv = sv * (fz * hf[t - 256]);
        ((_Float16*)(sm + OFF_RH))[t - 256] = (_Float16)rhv;
      }
    }
    if ((t & 3) == 0) {                 // EP-zr finish (128 threads)
      double S = 0.0, Q = 0.0;
      const double2* ep = (const double2*)(sm + OFF_EPZRP);
      #pragma unroll
      for (int i = 0; i < 8; ++i) { S += ep[i].x; Q += ep[i].y; }
      const double mean = S * (1.0 / 128.0);
      const double var = Q * (1.0 / 128.0) - mean * mean;
      const double den = sqrt(var + 1e-5) + 1e-5;
      const double s2e = (double)gse * ((de - mean) / den) + (double)bse;
      double se = 0.2 * (s1ezr_c + s2e) + 0.5;
      se = fmin(fmax(se, 0.0), 1.0);
      if (je < 64) ((double*)(sm + OFF_ZEE))[je] = se;
      else         ((double*)(sm + OFF_RHEP))[je - 64] = se * hepd[je - 64];
    }
    wg_barrier();  // B2

    // ---- Seg3: hh dot (t<256, conflict-free pages) | EP-hh dot (t>=256) ----
    float dh = 0.f;
    double deh = 0.0;
    if (t < 256) {
      const v8h* rhv8 = (const v8h*)(sm + OFF_RH);
      const v8h* uhv  = (const v8h*)(sm + OFF_UH);
      float c0 = 0.f, c1 = 0.f, c2 = 0.f, c3 = 0.f;
      #pragma unroll
      for (int p = 0; p < 32; ++p) {
        const v8h rc = rhv8[p];
        const v8h uc = uhv[p * 256 + t];
        c0 = fdot2_(pr<0>(rc), pr<0>(uc), c0);
        c1 = fdot2_(pr<1>(rc), pr<1>(uc), c1);
        c2 = fdot2_(pr<2>(rc), pr<2>(uc), c2);
        c3 = fdot2_(pr<3>(rc), pr<3>(uc), c3);
      }
      dh = (c0 + c1) + (c2 + c3);
      float s_ = dh, q_ = dh * dh;
      #pragma unroll
      for (int m = 1; m <= 32; m <<= 1) { s_ += __shfl_xor(s_, m); q_ += __shfl_xor(q_, m); }
      if ((t & 63) == 0) ((float2*)(sm + OFF_HHP))[w] = make_float2(s_, q_);
    } else {
      const double2* rp = (const double2*)((double*)(sm + OFF_RHEP) + 16 * qe);
      double acc = 0.0;
      #pragma unroll
      for (int i = 0; i < 8; ++i) {
        const double2 rv = rp[i];
        acc += rv.x * (double)ueh[2 * i] + rv.y * (double)ueh[2 * i + 1];
      }
      acc += __shfl_xor(acc, 1); acc += __shfl_xor(acc, 2);
      deh = acc;
      double es = deh, eq = deh * deh;
      #pragma unroll
      for (int m = 4; m <= 32; m <<= 1) { es += __shfl_xor(es, m); eq += __shfl_xor(eq, m); }
      if ((t & 63) == 0) ((double2*)(sm + OFF_EPHHP))[w - 4] = make_double2(es, eq);
    }
    wg_barrier();  // B3

    // ---- Seg4: main h update | EP hep update ----
    const int xm = maskl[tt];
    if (t < 256) {
      float S = 0.f, Q = 0.f;
      const float4* hp4 = (const float4*)(sm + OFF_HHP);
      #pragma unroll
      for (int i = 0; i < 2; ++i) { const float4 v = hp4[i]; S += v.x + v.z; Q += v.y + v.w; }
      const float mean = S * (1.f / 256.f);
      const float var = Q * (1.f / 256.f) - mean * mean;
      const float inv = 1.f / (sqrtf(var + 1e-5f) + 1e-5f);
      const float hhv = gh * ((dh - mean) * inv) + bh;
      const float z = ((float*)(sm + OFF_Z))[t];
      const float hzf = fz * hf[t];
      const float hn = z * hzf + (1.f - z) * tanhf(s1h_c + hhv);
      const float hc_ = (xm > 0) ? hn : hzf;
      hf[t] = hc_;
      const float ho = __shfl_xor(hc_, 1);
      if (!(t & 1)) {
        h2 p2; p2[0] = (_Float16)hc_; p2[1] = (_Float16)ho;
        ((h2*)(sm + OFF_H2))[t >> 1] = p2;
      }
    } else if ((t & 3) == 0) {          // EP finish (64 threads, col jeh)
      double S = 0.0, Q = 0.0;
      const double2* ep = (const double2*)(sm + OFF_EPHHP);
      #pragma unroll
      for (int i = 0; i < 4; ++i) { S += ep[i].x; Q += ep[i].y; }
      const double mean = S * (1.0 / 64.0);
      const double var = Q * (1.0 / 64.0) - mean * mean;
      const double den = sqrt(var + 1e-5) + 1e-5;
      const double hhe = (double)ghe * ((deh - mean) / den) + (double)bhe;
      const double ze = ((double*)(sm + OFF_ZEE))[jeh];
      const double hold = hepd[jeh];
      const double hepn = ze * hold + (1.0 - ze) * tanh(s1ehh_c + hhe);
      hepd[jeh] = (xm > 0) ? hepn : hold;
    }
    wg_barrier();  // B4

    s1zr_c = s1zr_n; s1h_c = s1h_n; s1ezr_c = s1ezr_n; s1ehh_c = s1ehh_n;
  }
  // final h write (step 2047)
  if (t < 256) out[((((size_t)b << 11) | 2047)) * 256 + t] = hf[t];
}

// ---------------------------------------------------------------------------
extern "C" void kernel_launch(void* const* d_in, const int* in_sizes, int n_in,
                              void* d_out, int out_size, void* d_ws, size_t ws_size,
                              hipStream_t stream)
{
  (void)in_sizes; (void)n_in; (void)out_size;
  const float* x       = (const float*)d_in[0];
  const int*   mask    = (const int*)d_in[1];
  const float* W       = (const float*)d_in[2];
  const float* U       = (const float*)d_in[3];
  const float* bvec    = (const float*)d_in[4];
  const float* gammas  = (const float*)d_in[5];
  const float* betas   = (const float*)d_in[6];
  const float* W_EP    = (const float*)d_in[7];
  const float* U_EP    = (const float*)d_in[8];
  const float* b_EP    = (const float*)d_in[9];
  const float* gammasE = (const float*)d_in[10];
  const float* betasE  = (const float*)d_in[11];
  const float* W1_EP   = (const float*)d_in[12];
  const float* b1_EP   = (const float*)d_in[13];
  float* out = (float*)d_out;

  const size_t NR = 131072;                 // B*T
  const size_t S1_SZ    = NR * 768 * 2;     // f16
  const size_t S1E64_SZ = NR * 192 * 8;     // f64
  const size_t S1E32_SZ = NR * 192 * 4;     // f32 fallback
  const size_t WSMALL = 262144 + 131072 + 393216 + 196608;
  const int s1e64 = (ws_size >= S1_SZ + S1E64_SZ + WSMALL) ? 1 : 0;
  const size_t S1E_SZ = s1e64 ? S1E64_SZ : S1E32_SZ;
  if (ws_size < S1_SZ + S1E32_SZ + WSMALL) return;  // cannot run

  char* ws = (char*)d_ws;
  size_t off = 0;
  void* s1e      = (void*)(ws + off);      off += S1E_SZ;
  _Float16* s1   = (_Float16*)(ws + off);  off += S1_SZ;
  _Float16* uzr  = (_Float16*)(ws + off);  off += 262144;
  _Float16* uh   = (_Float16*)(ws + off);  off += 131072;
  _Float16* wt   = (_Float16*)(ws + off);  off += 393216;
  float* wept    = (float*)(ws + off);     off += 196608;

  prep_kernel<<<dim3(1728), dim3(256), 0, stream>>>(
      W, U, W_EP, wt, uzr, uh, wept);
  ph1_main_kernel<<<dim3(8192), dim3(256), 0, stream>>>(
      x, wt, bvec, gammas, betas, s1);
  ph1_ep_kernel<<<dim3(8192), dim3(192), 0, stream>>>(
      x, wept, b_EP, gammasE, betasE, s1e, s1e64);

  hipFuncSetAttribute(reinterpret_cast<const void*>(scan_kernel),
                      hipFuncAttributeMaxDynamicSharedMemorySize, SCAN_LDS_BYTES);
  scan_kernel<<<dim3(64), dim3(512), SCAN_LDS_BYTES, stream>>>(
      uzr, uh, U_EP, s1, (const void*)s1e, s1e64, mask,
      gammas + 768, betas + 768, gammasE + 192, betasE + 192,
      W1_EP, b1_EP, out);
}

// Round 7
// 16670.012 us; speedup vs baseline: 1.6937x; 1.0009x over previous
//
#include <hip/hip_runtime.h>

// ---------------------------------------------------------------------------
// Encoder: B=64, T=2048, D=256, U=256, UEP=64
//  Phase 1a: s1  = ln(x @ W + b)    -> f16   [131072][768]
//  Phase 1b: s1e = ln(x @ W_EP + b) -> f64   [131072][192]  (exact fp64)
//  Phase 2 : 64 WGs x 512 thr, 2048 steps, 4 RAW barriers/step.
//    Uzr: 128 VGPR/thread as float[128], scalar-pinned.
//    amdgpu_waves_per_eu(2,2): tells the allocator occupancy is FIXED at
//    2 waves/EU (true: 144KB dynamic LDS -> 1 WG/CU), so it may use the
//    full 256-VGPR budget instead of capping at 128 for phantom occupancy.
//    Uh: LDS chunk-major pages (conflict-free).
//    EP GRU + is_end: fp64 (discrete round(sigmoid) must match reference).
//    s1/s1e register-prefetched 1 step ahead; raw barriers don't drain vmcnt.
// ---------------------------------------------------------------------------

typedef _Float16 h2  __attribute__((ext_vector_type(2)));
typedef _Float16 v8h __attribute__((ext_vector_type(8)));

__device__ __forceinline__ float fdot2_(h2 a, h2 b, float c) {
#if __has_builtin(__builtin_amdgcn_fdot2)
  return __builtin_amdgcn_fdot2(a, b, c, false);
#else
  return c + (float)a[0] * (float)b[0] + (float)a[1] * (float)b[1];
#endif
}

template <int I>
__device__ __forceinline__ h2 pr(v8h v) {
  h2 r; r[0] = v[2 * I]; r[1] = v[2 * I + 1]; return r;
}

// Raw barrier: order LDS (lgkmcnt) but leave global loads/stores in flight.
__device__ __forceinline__ void wg_barrier() {
  __builtin_amdgcn_sched_barrier(0);
  asm volatile("s_waitcnt lgkmcnt(0)" ::: "memory");
  __builtin_amdgcn_sched_barrier(0);
  __builtin_amdgcn_s_barrier();
  __builtin_amdgcn_sched_barrier(0);
}

// ---------------------------------------------------------------------------
// prep: weight transposes / conversions.
// blocks: [0,768) wt | [768,1280) uzr | [1280,1536) uh chunk-major | [1536,1728) wept
// ---------------------------------------------------------------------------
__global__ __launch_bounds__(256) void prep_kernel(
    const float* __restrict__ W, const float* __restrict__ U,
    const float* __restrict__ W_EP,
    _Float16* __restrict__ wt, _Float16* __restrict__ uzr,
    _Float16* __restrict__ uh, float* __restrict__ wept)
{
  const int blk = blockIdx.x;
  const int k = threadIdx.x;
  if (blk < 768) {                       // wt[j][k] = W[k][j]  (f16)
    const int j = blk;
    wt[(size_t)j * 256 + k] = (_Float16)W[(size_t)k * 768 + j];
  } else if (blk < 1280) {               // uzr[j][k] = U[k][j], j<512 (f16)
    const int j = blk - 768;
    uzr[(size_t)j * 256 + k] = (_Float16)U[(size_t)k * 768 + j];
  } else if (blk < 1536) {               // uh chunk-major: page p=k>>3, elem k&7
    const int j = blk - 1280;            // col 0..255
    const int p = k >> 3, e = k & 7;
    uh[((size_t)p * 256 + j) * 8 + e] = (_Float16)U[(size_t)k * 768 + 512 + j];
  } else {                               // wept[j][k] = W_EP[k][j] (f32)
    const int j = blk - 1536;
    wept[(size_t)j * 256 + k] = W_EP[(size_t)k * 192 + j];
  }
}

// ---------------------------------------------------------------------------
// Phase 1a: main s1 = ln(x@W + b, gammas[0], betas[0]) stored f16.
// ---------------------------------------------------------------------------
__global__ __launch_bounds__(256) void ph1_main_kernel(
    const float* __restrict__ x, const _Float16* __restrict__ wt,
    const float* __restrict__ bvec, const float* __restrict__ gam,
    const float* __restrict__ bet, _Float16* __restrict__ s1out)
{
  __shared__ __align__(16) _Float16 xs[16][256];   // 8 KB
  __shared__ float sp[16][768];                    // 48 KB
  const int tid = threadIdx.x;
  const size_t row0 = (size_t)blockIdx.x * 16;

  #pragma unroll
  for (int i = 0; i < 16; ++i)
    xs[i][tid] = (_Float16)x[(row0 + i) * 256 + tid];
  __syncthreads();

  #pragma unroll 1
  for (int cc = 0; cc < 3; ++cc) {
    const int col = cc * 256 + tid;
    const v8h* wp = (const v8h*)(wt + (size_t)col * 256);
    float acc[16];
    #pragma unroll
    for (int r = 0; r < 16; ++r) acc[r] = 0.f;
    #pragma unroll 4
    for (int c = 0; c < 32; ++c) {
      const v8h w8 = wp[c];
      #pragma unroll
      for (int r = 0; r < 16; ++r) {
        const v8h x8 = *(const v8h*)(&xs[r][c * 8]);
        acc[r] = fdot2_(pr<0>(x8), pr<0>(w8), acc[r]);
        acc[r] = fdot2_(pr<1>(x8), pr<1>(w8), acc[r]);
        acc[r] = fdot2_(pr<2>(x8), pr<2>(w8), acc[r]);
        acc[r] = fdot2_(pr<3>(x8), pr<3>(w8), acc[r]);
      }
    }
    const float bb = bvec[col];
    #pragma unroll
    for (int r = 0; r < 16; ++r) sp[r][col] = acc[r] + bb;
  }
  __syncthreads();

  const int w = tid >> 6, lane = tid & 63;
  for (int rr = 0; rr < 4; ++rr) {
    const int r = (w << 2) | rr;
    float vals[12], sum = 0.f, sq = 0.f;
    #pragma unroll
    for (int j = 0; j < 12; ++j) {
      const float v = sp[r][lane + (j << 6)];
      vals[j] = v; sum += v; sq += v * v;
    }
    #pragma unroll
    for (int m = 32; m >= 1; m >>= 1) {
      sum += __shfl_xor(sum, m); sq += __shfl_xor(sq, m);
    }
    const float mean = sum * (1.f / 768.f);
    const float var = sq * (1.f / 768.f) - mean * mean;
    const float inv = 1.f / (sqrtf(var + 1e-5f) + 1e-5f);
    #pragma unroll
    for (int j = 0; j < 12; ++j) {
      const int c = lane + (j << 6);
      s1out[(row0 + r) * 768 + c] =
          (_Float16)(gam[c] * ((vals[j] - mean) * inv) + bet[c]);
    }
  }
}

// ---------------------------------------------------------------------------
// Phase 1b: EP s1e = ln(x@W_EP + b_EP) in exact fp64, stored f64 (or f32).
// ---------------------------------------------------------------------------
__global__ __launch_bounds__(192) void ph1_ep_kernel(
    const float* __restrict__ x, const float* __restrict__ wept,
    const float* __restrict__ bvec, const float* __restrict__ gam,
    const float* __restrict__ bet, void* __restrict__ s1e, const int store64)
{
  __shared__ __align__(16) float xs[16][256];   // 16 KB
  __shared__ double sp[16][192];                // 24 KB
  const int tid = threadIdx.x;
  const size_t row0 = (size_t)blockIdx.x * 16;

  for (int idx = tid; idx < 4096; idx += 192)
    xs[idx >> 8][idx & 255] = x[row0 * 256 + idx];
  __syncthreads();

  {
    const float4* wp = (const float4*)(wept + (size_t)tid * 256);
    double acc[16];
    #pragma unroll
    for (int r = 0; r < 16; ++r) acc[r] = 0.0;
    #pragma unroll 2
    for (int c = 0; c < 64; ++c) {
      const float4 w4 = wp[c];
      #pragma unroll
      for (int r = 0; r < 16; ++r) {
        const float4 x4 = *(const float4*)(&xs[r][c * 4]);
        acc[r] += (double)x4.x * (double)w4.x;
        acc[r] += (double)x4.y * (double)w4.y;
        acc[r] += (double)x4.z * (double)w4.z;
        acc[r] += (double)x4.w * (double)w4.w;
      }
    }
    const double bb = (double)bvec[tid];
    #pragma unroll
    for (int r = 0; r < 16; ++r) sp[r][tid] = acc[r] + bb;
  }
  __syncthreads();

  const int w = tid >> 6, lane = tid & 63;
  for (int r = w; r < 16; r += 3) {
    double vals[3], sum = 0.0, sq = 0.0;
    #pragma unroll
    for (int j = 0; j < 3; ++j) {
      const double v = sp[r][lane + (j << 6)];
      vals[j] = v; sum += v; sq += v * v;
    }
    #pragma unroll
    for (int m = 32; m >= 1; m >>= 1) {
      sum += __shfl_xor(sum, m); sq += __shfl_xor(sq, m);
    }
    const double mean = sum * (1.0 / 192.0);
    const double var = sq * (1.0 / 192.0) - mean * mean;
    const double den = sqrt(var + 1e-5) + 1e-5;
    #pragma unroll
    for (int j = 0; j < 3; ++j) {
      const int c = lane + (j << 6);
      const double vv = (double)gam[c] * ((vals[j] - mean) / den) + (double)bet[c];
      if (store64) ((double*)s1e)[(row0 + r) * 192 + c] = vv;
      else         ((float*)s1e)[(row0 + r) * 192 + c] = (float)vv;
    }
  }
}

// ---------------------------------------------------------------------------
// Phase 2 LDS map (dynamic, 144192 B)
// ---------------------------------------------------------------------------
#define OFF_UH     0        /* 131072  f16 Uh chunk-major [32 pages][256 cols][8] */
#define OFF_MASK   131072   /* 8192    int mask row                               */
#define OFF_HEP    139264   /* 512     f64 hep[64]                                */
#define OFF_ZEE    139776   /* 512     f64 ze[64]                                 */
#define OFF_RHEP   140288   /* 512     f64 rhep[64]                               */
#define OFF_EPZRP  140800   /* 128     double2 epzrP[8]                           */
#define OFF_EPHHP  140928   /* 64      double2 ephhP[4]                           */
#define OFF_H2     140992   /* 512     f16 h packed h2[128]                       */
#define OFF_RH     141504   /* 512     f16 rh packed                              */
#define OFF_HF     142016   /* 1024    f32 h[256]                                 */
#define OFF_Z      143040   /* 1024    f32 z[256]                                 */
#define OFF_ZRP    144064   /* 64      float2 zrP[8]                              */
#define OFF_HHP    144128   /* 32      float2 hhP[4]                              */
#define OFF_FLAG   144160   /* 8       f32 flag[2]                                */
#define SCAN_LDS_BYTES 144192

__global__ __launch_bounds__(512)
__attribute__((amdgpu_waves_per_eu(2, 2)))
void scan_kernel(
    const _Float16* __restrict__ uzr_g, const _Float16* __restrict__ uh_g,
    const float* __restrict__ U_EP, const _Float16* __restrict__ s1,
    const void* __restrict__ s1e_v, const int s1e64,
    const int* __restrict__ mask,
    const float* __restrict__ gam1, const float* __restrict__ bet1,
    const float* __restrict__ gamep1, const float* __restrict__ betep1,
    const float* __restrict__ W1, const float* __restrict__ b1,
    float* __restrict__ out)
{
  extern __shared__ char sm[];
  const int t = threadIdx.x;
  const int b = blockIdx.x;
  const int w = t >> 6;
  const int je  = t >> 2;            // EP-zr col 0..127
  const int qe  = t & 3;             // EP K-slice
  const int jeh = (t & 255) >> 2;    // EP-hh col 0..63

  float*  hf    = (float*)(sm + OFF_HF);
  float*  flagp = (float*)(sm + OFF_FLAG);
  double* hepd  = (double*)(sm + OFF_HEP);
  int*    maskl = (int*)(sm + OFF_MASK);

  // ---- stage Uh (linear copy; layout already chunk-major) ----
  {
    const v8h* src = (const v8h*)uh_g;
    v8h* dst = (v8h*)(sm + OFF_UH);
    #pragma unroll
    for (int i = 0; i < 16; ++i) dst[i * 512 + t] = src[i * 512 + t];
  }
  // ---- stage mask row ----
  #pragma unroll
  for (int i = 0; i < 4; ++i) maskl[i * 512 + t] = mask[((size_t)b << 11) + i * 512 + t];

  // ---- Uzr full column t -> float[128], scalar-pinned (no remat/sink) ----
  float uz[128];
  {
    const float4* up = (const float4*)uzr_g + (size_t)t * 32;
    #pragma unroll
    for (int c = 0; c < 32; ++c) {
      const float4 v = up[c];
      uz[4 * c + 0] = v.x; uz[4 * c + 1] = v.y;
      uz[4 * c + 2] = v.z; uz[4 * c + 3] = v.w;
    }
  }
  #pragma unroll
  for (int i = 0; i < 128; ++i) asm volatile("" : "+v"(uz[i]));

  // ---- EP weights (f32 regs) ----
  float uez[16], ueh[16];
  #pragma unroll
  for (int i = 0; i < 16; ++i) uez[i] = U_EP[(size_t)(16 * qe + i) * 192 + je];
  #pragma unroll
  for (int i = 0; i < 16; ++i) ueh[i] = U_EP[(size_t)(16 * qe + i) * 192 + 128 + jeh];

  // ---- constants ----
  const float gz = gam1[t],                bz = bet1[t];
  const float gh = gam1[512 + (t & 255)],  bh = bet1[512 + (t & 255)];
  const float gse = gamep1[je],            bse = betep1[je];
  const float ghe = gamep1[128 + jeh],     bhe = betep1[128 + jeh];
  const double w1d = (double)W1[t & 63];
  const double b1d = (double)b1[0];
  const double* dptr = (const double*)s1e_v;
  const float*  fptr = (const float*)s1e_v;

  // ---- init state ----
  if (t < 128) { h2 z2; z2[0] = (_Float16)0.f; z2[1] = (_Float16)0.f;
                 ((h2*)(sm + OFF_H2))[t] = z2; }
  if (t < 256) hf[t] = 0.f;
  if (t < 64)  hepd[t] = 0.0;
  if (t < 2)   flagp[t] = 0.f;

  // ---- prefetch step 0 ----
  const size_t n0 = (size_t)b << 11;
  float  s1zr_c = (float)s1[n0 * 768 + t];
  float  s1h_c  = (float)s1[n0 * 768 + 512 + (t & 255)];
  double s1ezr_c = s1e64 ? dptr[n0 * 192 + je]
                         : (double)fptr[n0 * 192 + je];
  double s1ehh_c = s1e64 ? dptr[n0 * 192 + 128 + jeh]
                         : (double)fptr[n0 * 192 + 128 + jeh];
  __syncthreads();

  for (int tt = 0; tt < 2048; ++tt) {
    const size_t n = ((size_t)b << 11) | (size_t)tt;
    const float fz = (flagp[tt & 1] > 0.5f) ? 0.f : 1.f;

    // ---- Seg1: deferred h-write | prefetch t+1 | is_end | zr dot | EP-zr dot
    if (tt > 0 && t < 256) out[(n - 1) * 256 + t] = hf[t];

    const int ttn = (tt < 2047) ? tt + 1 : 2047;
    const size_t np1 = ((size_t)b << 11) | (size_t)ttn;
    const float  s1zr_n = (float)s1[np1 * 768 + t];
    const float  s1h_n  = (float)s1[np1 * 768 + 512 + (t & 255)];
    const double s1ezr_n = s1e64 ? dptr[np1 * 192 + je]
                                 : (double)fptr[np1 * 192 + je];
    const double s1ehh_n = s1e64 ? dptr[np1 * 192 + 128 + jeh]
                                 : (double)fptr[np1 * 192 + 128 + jeh];

    if (w == 7) {                       // is_end from hep (pre-update)
      double p = hepd[t & 63] * w1d;
      #pragma unroll
      for (int m = 1; m <= 32; m <<= 1) p += __shfl_xor(p, m);
      if (t == 448) {
        const float e = ((p + b1d) > 0.0) ? 1.f : 0.f;
        flagp[(tt + 1) & 1] = e;
        out[(size_t)33554432 + n] = e;
      }
    }

    float d;                            // zr dot: full-K column t
    {
      const v8h* hv = (const v8h*)(sm + OFF_H2);
      float a0 = 0.f, a1 = 0.f, a2 = 0.f, a3 = 0.f;
      #pragma unroll
      for (int c = 0; c < 32; ++c) {
        const v8h hc = hv[c];
        a0 = fdot2_(pr<0>(hc), __builtin_bit_cast(h2, uz[4 * c + 0]), a0);
        a1 = fdot2_(pr<1>(hc), __builtin_bit_cast(h2, uz[4 * c + 1]), a1);
        a2 = fdot2_(pr<2>(hc), __builtin_bit_cast(h2, uz[4 * c + 2]), a2);
        a3 = fdot2_(pr<3>(hc), __builtin_bit_cast(h2, uz[4 * c + 3]), a3);
      }
      d = ((a0 + a1) + (a2 + a3)) * fz;
      float s_ = d, q_ = d * d;
      #pragma unroll
      for (int m = 1; m <= 32; m <<= 1) { s_ += __shfl_xor(s_, m); q_ += __shfl_xor(q_, m); }
      if ((t & 63) == 0) ((float2*)(sm + OFF_ZRP))[w] = make_float2(s_, q_);
    }
    double de;                          // EP-zr dot: col je, K-slice qe
    {
      const double2* hp = (const double2*)(hepd + 16 * qe);
      double acc = 0.0;
      #pragma unroll
      for (int i = 0; i < 8; ++i) {
        const double2 hv2 = hp[i];
        acc += hv2.x * (double)uez[2 * i] + hv2.y * (double)uez[2 * i + 1];
      }
      acc += __shfl_xor(acc, 1); acc += __shfl_xor(acc, 2);
      de = acc;
      double es = de, eq = de * de;
      #pragma unroll
      for (int m = 4; m <= 32; m <<= 1) { es += __shfl_xor(es, m); eq += __shfl_xor(eq, m); }
      if ((t & 63) == 0) ((double2*)(sm + OFF_EPZRP))[w] = make_double2(es, eq);
    }
    wg_barrier();  // B1

    // ---- Seg2: LN512 -> z / rh | EP LN128 -> ze / rhep ----
    {
      float S = 0.f, Q = 0.f;
      const float4* zp = (const float4*)(sm + OFF_ZRP);
      #pragma unroll
      for (int i = 0; i < 4; ++i) { const float4 v = zp[i]; S += v.x + v.z; Q += v.y + v.w; }
      const float mean = S * (1.f / 512.f);
      const float var = Q * (1.f / 512.f) - mean * mean;
      const float inv = 1.f / (sqrtf(var + 1e-5f) + 1e-5f);
      const float s2v = gz * ((d - mean) * inv) + bz;
      float sv = 0.2f * (s1zr_c + s2v) + 0.5f;
      sv = fminf(fmaxf(sv, 0.f), 1.f);
      if (t < 256) ((float*)(sm + OFF_Z))[t] = sv;
      else {
        const float rhv = sv * (fz * hf[t - 256]);
        ((_Float16*)(sm + OFF_RH))[t - 256] = (_Float16)rhv;
      }
    }
    if ((t & 3) == 0) {                 // EP-zr finish (128 threads)
      double S = 0.0, Q = 0.0;
      const double2* ep = (const double2*)(sm + OFF_EPZRP);
      #pragma unroll
      for (int i = 0; i < 8; ++i) { S += ep[i].x; Q += ep[i].y; }
      const double mean = S * (1.0 / 128.0);
      const double var = Q * (1.0 / 128.0) - mean * mean;
      const double den = sqrt(var + 1e-5) + 1e-5;
      const double s2e = (double)gse * ((de - mean) / den) + (double)bse;
      double se = 0.2 * (s1ezr_c + s2e) + 0.5;
      se = fmin(fmax(se, 0.0), 1.0);
      if (je < 64) ((double*)(sm + OFF_ZEE))[je] = se;
      else         ((double*)(sm + OFF_RHEP))[je - 64] = se * hepd[je - 64];
    }
    wg_barrier();  // B2

    // ---- Seg3: hh dot (t<256, conflict-free pages) | EP-hh dot (t>=256) ----
    float dh = 0.f;
    double deh = 0.0;
    if (t < 256) {
      const v8h* rhv8 = (const v8h*)(sm + OFF_RH);
      const v8h* uhv  = (const v8h*)(sm + OFF_UH);
      float c0 = 0.f, c1 = 0.f, c2 = 0.f, c3 = 0.f;
      #pragma unroll
      for (int p = 0; p < 32; ++p) {
        const v8h rc = rhv8[p];
        const v8h uc = uhv[p * 256 + t];
        c0 = fdot2_(pr<0>(rc), pr<0>(uc), c0);
        c1 = fdot2_(pr<1>(rc), pr<1>(uc), c1);
        c2 = fdot2_(pr<2>(rc), pr<2>(uc), c2);
        c3 = fdot2_(pr<3>(rc), pr<3>(uc), c3);
      }
      dh = (c0 + c1) + (c2 + c3);
      float s_ = dh, q_ = dh * dh;
      #pragma unroll
      for (int m = 1; m <= 32; m <<= 1) { s_ += __shfl_xor(s_, m); q_ += __shfl_xor(q_, m); }
      if ((t & 63) == 0) ((float2*)(sm + OFF_HHP))[w] = make_float2(s_, q_);
    } else {
      const double2* rp = (const double2*)((double*)(sm + OFF_RHEP) + 16 * qe);
      double acc = 0.0;
      #pragma unroll
      for (int i = 0; i < 8; ++i) {
        const double2 rv = rp[i];
        acc += rv.x * (double)ueh[2 * i] + rv.y * (double)ueh[2 * i + 1];
      }
      acc += __shfl_xor(acc, 1); acc += __shfl_xor(acc, 2);
      deh = acc;
      double es = deh, eq = deh * deh;
      #pragma unroll
      for (int m = 4; m <= 32; m <<= 1) { es += __shfl_xor(es, m); eq += __shfl_xor(eq, m); }
      if ((t & 63) == 0) ((double2*)(sm + OFF_EPHHP))[w - 4] = make_double2(es, eq);
    }
    wg_barrier();  // B3

    // ---- Seg4: main h update | EP hep update ----
    const int xm = maskl[tt];
    if (t < 256) {
      float S = 0.f, Q = 0.f;
      const float4* hp4 = (const float4*)(sm + OFF_HHP);
      #pragma unroll
      for (int i = 0; i < 2; ++i) { const float4 v = hp4[i]; S += v.x + v.z; Q += v.y + v.w; }
      const float mean = S * (1.f / 256.f);
      const float var = Q * (1.f / 256.f) - mean * mean;
      const float inv = 1.f / (sqrtf(var + 1e-5f) + 1e-5f);
      const float hhv = gh * ((dh - mean) * inv) + bh;
      const float z = ((float*)(sm + OFF_Z))[t];
      const float hzf = fz * hf[t];
      const float hn = z * hzf + (1.f - z) * tanhf(s1h_c + hhv);
      const float hc_ = (xm > 0) ? hn : hzf;
      hf[t] = hc_;
      const float ho = __shfl_xor(hc_, 1);
      if (!(t & 1)) {
        h2 p2; p2[0] = (_Float16)hc_; p2[1] = (_Float16)ho;
        ((h2*)(sm + OFF_H2))[t >> 1] = p2;
      }
    } else if ((t & 3) == 0) {          // EP finish (64 threads, col jeh)
      double S = 0.0, Q = 0.0;
      const double2* ep = (const double2*)(sm + OFF_EPHHP);
      #pragma unroll
      for (int i = 0; i < 4; ++i) { S += ep[i].x; Q += ep[i].y; }
      const double mean = S * (1.0 / 64.0);
      const double var = Q * (1.0 / 64.0) - mean * mean;
      const double den = sqrt(var + 1e-5) + 1e-5;
      const double hhe = (double)ghe * ((deh - mean) / den) + (double)bhe;
      const double ze = ((double*)(sm + OFF_ZEE))[jeh];
      const double hold = hepd[jeh];
      const double hepn = ze * hold + (1.0 - ze) * tanh(s1ehh_c + hhe);
      hepd[jeh] = (xm > 0) ? hepn : hold;
    }
    wg_barrier();  // B4

    s1zr_c = s1zr_n; s1h_c = s1h_n; s1ezr_c = s1ezr_n; s1ehh_c = s1ehh_n;
  }
  // final h write (step 2047)
  if (t < 256) out[((((size_t)b << 11) | 2047)) * 256 + t] = hf[t];
}

// ---------------------------------------------------------------------------
extern "C" void kernel_launch(void* const* d_in, const int* in_sizes, int n_in,
                              void* d_out, int out_size, void* d_ws, size_t ws_size,
                              hipStream_t stream)
{
  (void)in_sizes; (void)n_in; (void)out_size;
  const float* x       = (const float*)d_in[0];
  const int*   mask    = (const int*)d_in[1];
  const float* W       = (const float*)d_in[2];
  const float* U       = (const float*)d_in[3];
  const float* bvec    = (const float*)d_in[4];
  const float* gammas  = (const float*)d_in[5];
  const float* betas   = (const float*)d_in[6];
  const float* W_EP    = (const float*)d_in[7];
  const float* U_EP    = (const float*)d_in[8];
  const float* b_EP    = (const float*)d_in[9];
  const float* gammasE = (const float*)d_in[10];
  const float* betasE  = (const float*)d_in[11];
  const float* W1_EP   = (const float*)d_in[12];
  const float* b1_EP   = (const float*)d_in[13];
  float* out = (float*)d_out;

  const size_t NR = 131072;                 // B*T
  const size_t S1_SZ    = NR * 768 * 2;     // f16
  const size_t S1E64_SZ = NR * 192 * 8;     // f64
  const size_t S1E32_SZ = NR * 192 * 4;     // f32 fallback
  const size_t WSMALL = 262144 + 131072 + 393216 + 196608;
  const int s1e64 = (ws_size >= S1_SZ + S1E64_SZ + WSMALL) ? 1 : 0;
  const size_t S1E_SZ = s1e64 ? S1E64_SZ : S1E32_SZ;
  if (ws_size < S1_SZ + S1E32_SZ + WSMALL) return;  // cannot run

  char* ws = (char*)d_ws;
  size_t off = 0;
  void* s1e      = (void*)(ws + off);      off += S1E_SZ;
  _Float16* s1   = (_Float16*)(ws + off);  off += S1_SZ;
  _Float16* uzr  = (_Float16*)(ws + off);  off += 262144;
  _Float16* uh   = (_Float16*)(ws + off);  off += 131072;
  _Float16* wt   = (_Float16*)(ws + off);  off += 393216;
  float* wept    = (float*)(ws + off);     off += 196608;

  prep_kernel<<<dim3(1728), dim3(256), 0, stream>>>(
      W, U, W_EP, wt, uzr, uh, wept);
  ph1_main_kernel<<<dim3(8192), dim3(256), 0, stream>>>(
      x, wt, bvec, gammas, betas, s1);
  ph1_ep_kernel<<<dim3(8192), dim3(192), 0, stream>>>(
      x, wept, b_EP, gammasE, betasE, s1e, s1e64);

  hipFuncSetAttribute(reinterpret_cast<const void*>(scan_kernel),
                      hipFuncAttributeMaxDynamicSharedMemorySize, SCAN_LDS_BYTES);
  scan_kernel<<<dim3(64), dim3(512), SCAN_LDS_BYTES, stream>>>(
      uzr, uh, U_EP, s1, (const void*)s1e, s1e64, mask,
      gammas + 768, betas + 768, gammasE + 192, betasE + 192,
      W1_EP, b1_EP, out);
}